// Round 9
// baseline (410.123 us; speedup 1.0000x reference)
//
#include <hip/hip_runtime.h>

typedef unsigned short u16;
typedef __attribute__((ext_vector_type(4))) short s16x4;
typedef __attribute__((ext_vector_type(8))) short s16x8;
typedef __attribute__((ext_vector_type(4))) float f32x4;

__device__ __forceinline__ float bf2f_(u16 b) { return __uint_as_float(((unsigned)b) << 16); }
__device__ __forceinline__ u16 f2bf_(float f) {
  unsigned u = __float_as_uint(f);
  return (u16)((u + 0x7FFFu + ((u >> 16) & 1u)) >> 16);
}

__device__ __forceinline__ void edge_decode(const int* ei, int e, int E, const int* flags,
                                            int& src, int& dst) {
  bool is64 = flags[1] < 100;
  src = is64 ? ei[2 * e] : ei[e];
  dst = is64 ? ei[2 * E + 2 * e] : ei[E + e];
}

// ---------------- setup ----------------
__global__ void k_zeroi(int* a, int n) {
  int i = blockIdx.x * 256 + threadIdx.x;
  if (i < n) a[i] = 0;
}

__global__ __launch_bounds__(256) void k_detect(const u16* __restrict__ xb,
                                                const int* __restrict__ ei,
                                                int* __restrict__ flags) {
  int i = blockIdx.x * 256 + threadIdx.x;  // 4096 threads
  int e8 = (xb[2 * i] >> 7) & 0xFF;
  int sane = (e8 >= 100 && e8 <= 140) ? 1 : 0;
  int nz = (ei[2 * i + 1] != 0) ? 1 : 0;
  #pragma unroll
  for (int off = 32; off; off >>= 1) { sane += __shfl_down(sane, off); nz += __shfl_down(nz, off); }
  if ((threadIdx.x & 63) == 0) { atomicAdd(&flags[0], sane); atomicAdd(&flags[1], nz); }
}

__global__ void k_loadall(const void* x, const void* wd, const void* bd, const void* wu,
                          const void* bu, const void* pw,
                          float* xin, float* Wdf, float* bdf, float* Wuf, float* buf_, float* pwf,
                          const int* __restrict__ flags) {
  int i = blockIdx.x * 256 + threadIdx.x;
  const void* src; float* dst; int off;
  if (i < 524288) { src = x; dst = xin; off = i; }
  else if (i < 589824) { src = wd; dst = Wdf; off = i - 524288; }
  else if (i < 590336) { src = bd; dst = bdf; off = i - 589824; }
  else if (i < 639488) { src = wu; dst = Wuf; off = i - 590336; }
  else if (i < 639872) { src = bu; dst = buf_; off = i - 639488; }
  else if (i < 640256) { src = pw; dst = pwf; off = i - 639872; }
  else return;
  bool isbf = flags[0] >= 2048;
  dst[off] = isbf ? bf2f_(((const u16*)src)[off]) : ((const float*)src)[off];
}

__global__ void k_fill0(float4* __restrict__ p, long n4) {
  long i = blockIdx.x * 256L + threadIdx.x;
  long stride = (long)gridDim.x * 256L;
  for (; i < n4; i += stride) p[i] = make_float4(0.f, 0.f, 0.f, 0.f);
}

// ---------------- CSR build ----------------
__global__ void k_degcnt(const int* __restrict__ ei, int E, int n, const int* __restrict__ flags,
                         int* __restrict__ indeg, int* __restrict__ outdeg, int* __restrict__ indeg2) {
  int e = blockIdx.x * 256 + threadIdx.x;
  if (e >= E) return;
  int src, dst; edge_decode(ei, e, E, flags, src, dst);
  if (src < 0 || src >= n || dst < 0 || dst >= n) return;
  atomicAdd(&indeg2[dst], 1);
  if (src == dst) return;
  atomicAdd(&indeg[dst], 1);
  atomicAdd(&outdeg[src], 1);
}

__global__ __launch_bounds__(1024) void k_scan3(const int* __restrict__ d0, const int* __restrict__ d1,
                                                const int* __restrict__ d2,
                                                int* o0, int* o1, int* o2,
                                                int* c0, int* c1, int* c2, int n) {
  __shared__ int part[1024];
  int t = threadIdx.x;
  int per = n / 1024;
  for (int pass = 0; pass < 3; ++pass) {
    const int* deg = pass == 0 ? d0 : (pass == 1 ? d1 : d2);
    int* off = pass == 0 ? o0 : (pass == 1 ? o1 : o2);
    int* cur = pass == 0 ? c0 : (pass == 1 ? c1 : c2);
    int local[8];
    int s = 0;
    for (int j = 0; j < per; ++j) { local[j] = s; s += deg[t * per + j]; }
    part[t] = s;
    __syncthreads();
    for (int d = 1; d < 1024; d <<= 1) {
      int v = (t >= d) ? part[t - d] : 0;
      __syncthreads();
      part[t] += v;
      __syncthreads();
    }
    int base = (t == 0) ? 0 : part[t - 1];
    for (int j = 0; j < per; ++j) {
      off[t * per + j] = base + local[j];
      cur[t * per + j] = base + local[j];
    }
    if (t == 1023) off[n] = part[1023];
    __syncthreads();
  }
}

__global__ void k_csrfill(const int* __restrict__ ei, int E, int n, const int* __restrict__ flags,
                          int* __restrict__ incur, int* __restrict__ outcur, int* __restrict__ incur2,
                          int* __restrict__ inlist, int* __restrict__ outlist, int* __restrict__ inlist2) {
  int e = blockIdx.x * 256 + threadIdx.x;
  if (e >= E) return;
  int src, dst; edge_decode(ei, e, E, flags, src, dst);
  if (src < 0 || src >= n || dst < 0 || dst >= n) return;
  inlist2[atomicAdd(&incur2[dst], 1)] = src;
  if (src == dst) return;
  inlist[atomicAdd(&incur[dst], 1)] = src;
  outlist[atomicAdd(&outcur[src], 1)] = dst;
}

// wave-parallel row sort (deterministic contents) + dinv0 from counts
__global__ __launch_bounds__(256) void k_rowsort(const int* __restrict__ inoff2,
                                                 const int* __restrict__ inlist2,
                                                 int* __restrict__ outlist2,
                                                 const int* __restrict__ indeg2,
                                                 float* __restrict__ dinv, int n) {
  int wave = threadIdx.x >> 6, lane = threadIdx.x & 63;
  int row = blockIdx.x * 4 + wave;
  if (row >= n) return;
  int ib = inoff2[row], ie = inoff2[row + 1];
  int L = ie - ib;
  for (int i = lane; i < L; i += 64) {
    int ki = inlist2[ib + i];
    int rank = 0;
    for (int j = 0; j < L; ++j) {
      int kj = inlist2[ib + j];
      rank += (kj < ki || (kj == ki && j < i)) ? 1 : 0;
    }
    outlist2[ib + rank] = ki;
  }
  if (lane == 0) dinv[row] = rsqrtf((float)indeg2[row] + 2.0f);
}

// ---------------- sparse L1 pool (join + 2*Ao edge term in one kernel) ----------------
__global__ __launch_bounds__(256) void k_spool(const int* __restrict__ inoff, const int* __restrict__ inlist,
                                               const int* __restrict__ outoff, const int* __restrict__ outlist,
                                               const int* __restrict__ inv, float* __restrict__ C,
                                               int M, int n, int njoin,
                                               const int* __restrict__ ei, int E, const int* __restrict__ flags) {
  int wave = threadIdx.x >> 6, lane = threadIdx.x & 63;
  if ((int)blockIdx.x < njoin) {
    int v = blockIdx.x * 4 + wave;
    if (v >= n) return;
    int ib = inoff[v], ni = inoff[v + 1] - ib;
    int ob = outoff[v], no = outoff[v + 1] - ob;
    int tot = ni * no;
    for (int p = lane; p < tot; p += 64) {
      int oi = p / ni, ii = p - oi * ni;
      int i = outlist[ob + oi];
      int j = inlist[ib + ii];
      if (i == j) continue;
      int ri = inv[i], rj = inv[j];
      if (ri >= 0 && rj >= 0) atomicAdd(&C[(size_t)ri * M + rj], 1.0f);
    }
  } else {
    int e = (blockIdx.x - njoin) * 256 + threadIdx.x;
    if (e >= E) return;
    int src, dst; edge_decode(ei, e, E, flags, src, dst);
    if (src < 0 || src >= n || dst < 0 || dst >= n || src == dst) return;
    int ri = inv[dst], rj = inv[src];
    if (ri >= 0 && rj >= 0) atomicAdd(&C[(size_t)ri * M + rj], 2.0f);
  }
}

// ---------------- fused xW kernel ----------------
// MODE: 0 plain x, 1 gather (x[perm[r]]*ts), 2 unpool (res[r]+prev[inv[r]])
// CDINV: 1 -> compute dinv from A rowsums (and cache); 0 -> read cached
// WT: 1 -> also write yTh/yTl bf16 hi/lo transpose chunks
template<int MODE, int CDINV, int WT>
__global__ __launch_bounds__(256) void k_xw(const float* __restrict__ x, const float* __restrict__ res,
                                            const float* __restrict__ prev,
                                            const int* __restrict__ perm, const int* __restrict__ invm,
                                            const float* __restrict__ ts,
                                            const float* __restrict__ A, const float* __restrict__ W,
                                            float* __restrict__ dinv, float* __restrict__ yp,
                                            u16* __restrict__ yTh, u16* __restrict__ yTl, int n) {
  __shared__ float xs_[16 * 128];
  __shared__ float ds[16];
  int t = threadIdx.x;
  int row0 = blockIdx.x * 16;
  for (int e = t; e < 16 * 128; e += 256) {
    int r = e >> 7, c = e & 127;
    int gr = row0 + r;
    float v;
    if (MODE == 0) v = x[(size_t)gr * 128 + c];
    else if (MODE == 1) { int p0 = perm[gr]; v = x[(size_t)p0 * 128 + c] * ts[p0]; }
    else {
      int ir = invm[gr];
      v = res[(size_t)gr * 128 + c];
      if (ir >= 0) v += prev[(size_t)ir * 128 + c];
    }
    xs_[e] = v;
  }
  int wave = t >> 6, lane = t & 63;
  if (CDINV) {
    #pragma unroll
    for (int rr = 0; rr < 4; ++rr) {
      int r = wave * 4 + rr;
      const float* Ar = A + (size_t)(row0 + r) * n;
      float s = 0.f;
      for (int j = lane; j < n; j += 64) s += Ar[j];
      #pragma unroll
      for (int off = 32; off; off >>= 1) s += __shfl_down(s, off);
      if (lane == 0) {
        float d = rsqrtf(s + 2.0f);
        ds[r] = d;
        dinv[row0 + r] = d;
      }
    }
  } else {
    if (t < 16) ds[t] = dinv[row0 + t];
  }
  __syncthreads();
  int c = t & 127, rh = t >> 7;
  float acc[8];
  #pragma unroll
  for (int ri = 0; ri < 8; ++ri) acc[ri] = 0.f;
  for (int k = 0; k < 128; ++k) {
    float wv = W[k * 128 + c];
    #pragma unroll
    for (int ri = 0; ri < 8; ++ri) acc[ri] += xs_[(rh * 8 + ri) * 128 + k] * wv;
  }
  s16x8 h, l;
  #pragma unroll
  for (int ri = 0; ri < 8; ++ri) {
    int r = row0 + rh * 8 + ri;
    float v = ds[rh * 8 + ri] * acc[ri];
    yp[(size_t)r * 128 + c] = v;
    if (WT) {
      u16 hb = f2bf_(v);
      h[ri] = (short)hb;
      l[ri] = (short)f2bf_(v - bf2f_(hb));
    }
  }
  if (WT) {
    int rbase = row0 + rh * 8;
    *(s16x8*)&yTh[(size_t)c * n + rbase] = h;
    *(s16x8*)&yTl[(size_t)c * n + rbase] = l;
  }
}

// ---------------- fused CSR SpMV + GCN epilogue (+optional score) ----------------
template<int FINAL, int SCORE>
__global__ __launch_bounds__(256) void k_spmv(const int* __restrict__ inoff2, const int* __restrict__ inlist2,
                                              const float* __restrict__ y, const float* __restrict__ dinv,
                                              const float* __restrict__ b, const float* __restrict__ w,
                                              float* __restrict__ outf, void* __restrict__ outv,
                                              float* __restrict__ ts,
                                              int n, int act, const int* __restrict__ flags) {
  int wave = threadIdx.x >> 6, lane = threadIdx.x & 63;
  int i = blockIdx.x * 4 + wave;
  if (i >= n) return;
  int ib = inoff2[i], ie = inoff2[i + 1];
  float z0 = 0.f, z1 = 0.f;
  for (int e = ib; e < ie; ++e) {
    int s = inlist2[e];
    z0 += y[(size_t)s * 128 + lane];
    z1 += y[(size_t)s * 128 + 64 + lane];
  }
  float di = dinv[i];
  float y0 = y[(size_t)i * 128 + lane], y1 = y[(size_t)i * 128 + 64 + lane];
  float v0 = di * (z0 + 2.0f * y0) + b[lane];
  float v1 = di * (z1 + 2.0f * y1) + b[64 + lane];
  if (act) { v0 = (v0 >= 0.f) ? v0 : 0.01f * v0; v1 = (v1 >= 0.f) ? v1 : 0.01f * v1; }
  if (FINAL) {
    if (flags[0] >= 2048) {
      ((u16*)outv)[(size_t)i * 128 + lane] = f2bf_(v0);
      ((u16*)outv)[(size_t)i * 128 + 64 + lane] = f2bf_(v1);
    } else {
      ((float*)outv)[(size_t)i * 128 + lane] = v0;
      ((float*)outv)[(size_t)i * 128 + 64 + lane] = v1;
    }
  } else {
    outf[(size_t)i * 128 + lane] = v0;
    outf[(size_t)i * 128 + 64 + lane] = v1;
  }
  if (SCORE) {
    float w0 = w[lane], w1 = w[64 + lane];
    float nr = w0 * w0 + w1 * w1;
    float dt = v0 * w0 + v1 * w1;
    #pragma unroll
    for (int off = 32; off; off >>= 1) { nr += __shfl_down(nr, off); dt += __shfl_down(dt, off); }
    if (lane == 0) ts[i] = tanhf(dt / sqrtf(nr));
  }
}

// ---------------- dense zgemm (n<=2048) ----------------
template<int ALO>
__global__ __launch_bounds__(256) void k_zgemm_mfma(const float* __restrict__ A,
                                                    const u16* __restrict__ yTh,
                                                    const u16* __restrict__ yTl,
                                                    float* __restrict__ zpart,
                                                    int n, int kchunk) {
  __shared__ __align__(16) u16 ah_[128 * 64];
  __shared__ __align__(16) u16 al_[ALO ? 128 * 64 : 8];
  __shared__ __align__(16) u16 bh_[128 * 64];
  __shared__ __align__(16) u16 bl_[128 * 64];
  int t = threadIdx.x;
  int row0 = blockIdx.x * 128;
  int s = blockIdx.y;
  int kbase = s * kchunk;
  int wave = t >> 6, lane = t & 63;
  int wr = wave >> 1, wc = wave & 1;
  int lrow = lane & 15, kb = lane >> 4;
  const f32x4 z4 = {0.f, 0.f, 0.f, 0.f};
  f32x4 acc[4][4];
  #pragma unroll
  for (int a = 0; a < 4; ++a)
    #pragma unroll
    for (int b = 0; b < 4; ++b) acc[a][b] = z4;

  for (int k0 = 0; k0 < kchunk; k0 += 64) {
    int koff = kbase + k0;
    __syncthreads();
    #pragma unroll
    for (int it = 0; it < 8; ++it) {
      int q = it * 256 + t;
      int r = q >> 4, i4 = q & 15;
      int g = i4 >> 1, h4 = (i4 & 1) * 4;
      float4 v = *(const float4*)&A[(size_t)(row0 + r) * n + koff + i4 * 4];
      float vv[4] = {v.x, v.y, v.z, v.w};
      s16x4 hh, ll;
      #pragma unroll
      for (int j = 0; j < 4; ++j) {
        u16 hb = f2bf_(vv[j]);
        hh[j] = (short)hb;
        if (ALO) ll[j] = (short)f2bf_(vv[j] - bf2f_(hb));
      }
      int ld = r * 64 + ((g ^ (r & 7)) << 3) + h4;
      *(s16x4*)&ah_[ld] = hh;
      if (ALO) *(s16x4*)&al_[ld] = ll;
    }
    #pragma unroll
    for (int it = 0; it < 4; ++it) {
      int q = it * 256 + t;
      int r = q >> 3, g = q & 7;
      int ld = r * 64 + ((g ^ (r & 7)) << 3);
      *(s16x8*)&bh_[ld] = *(const s16x8*)(yTh + (size_t)r * n + koff + g * 8);
      *(s16x8*)&bl_[ld] = *(const s16x8*)(yTl + (size_t)r * n + koff + g * 8);
    }
    __syncthreads();
    #pragma unroll
    for (int ks = 0; ks < 2; ++ks) {
      int gg = ks * 4 + kb;
      int gsw = (gg ^ (lrow & 7)) << 3;
      s16x8 af[4], alf[4], bhf[4], blf[4];
      #pragma unroll
      for (int mi = 0; mi < 4; ++mi) {
        int row = wr * 64 + mi * 16 + lrow;
        af[mi] = *(const s16x8*)&ah_[row * 64 + gsw];
        if (ALO) alf[mi] = *(const s16x8*)&al_[row * 64 + gsw];
      }
      #pragma unroll
      for (int ni = 0; ni < 4; ++ni) {
        int row = wc * 64 + ni * 16 + lrow;
        bhf[ni] = *(const s16x8*)&bh_[row * 64 + gsw];
        blf[ni] = *(const s16x8*)&bl_[row * 64 + gsw];
      }
      #pragma unroll
      for (int mi = 0; mi < 4; ++mi)
        #pragma unroll
        for (int ni = 0; ni < 4; ++ni) {
          acc[mi][ni] = __builtin_amdgcn_mfma_f32_16x16x32_bf16(af[mi], bhf[ni], acc[mi][ni], 0, 0, 0);
          acc[mi][ni] = __builtin_amdgcn_mfma_f32_16x16x32_bf16(af[mi], blf[ni], acc[mi][ni], 0, 0, 0);
          if (ALO) {
            acc[mi][ni] = __builtin_amdgcn_mfma_f32_16x16x32_bf16(alf[mi], bhf[ni], acc[mi][ni], 0, 0, 0);
            acc[mi][ni] = __builtin_amdgcn_mfma_f32_16x16x32_bf16(alf[mi], blf[ni], acc[mi][ni], 0, 0, 0);
          }
        }
    }
  }
  int rbase = (lane >> 4) * 4;
  #pragma unroll
  for (int mi = 0; mi < 4; ++mi)
    #pragma unroll
    for (int ni = 0; ni < 4; ++ni)
      #pragma unroll
      for (int j = 0; j < 4; ++j) {
        int gi = row0 + wr * 64 + mi * 16 + rbase + j;
        int gj = wc * 64 + ni * 16 + (lane & 15);
        zpart[((size_t)s * n + gi) * 128 + gj] = acc[mi][ni][j];
      }
}

// row-per-wave epilogue: v = dinv*(sum_s zpart + 2*yp) + b; leaky; optional score
template<int SCORE>
__global__ __launch_bounds__(256) void k_epi(const float* __restrict__ zpart, const float* __restrict__ yp,
                                             const float* __restrict__ dinv, const float* __restrict__ b,
                                             const float* __restrict__ w,
                                             float* __restrict__ outf, float* __restrict__ ts,
                                             int n, int S, int act) {
  int wave = threadIdx.x >> 6, lane = threadIdx.x & 63;
  int r = blockIdx.x * 4 + wave;
  if (r >= n) return;
  float z0 = 0.f, z1 = 0.f;
  for (int s = 0; s < S; ++s) {
    const float* zp = zpart + ((size_t)s * n + r) * 128;
    z0 += zp[lane];
    z1 += zp[64 + lane];
  }
  float di = dinv[r];
  float v0 = di * (z0 + 2.0f * yp[(size_t)r * 128 + lane]) + b[lane];
  float v1 = di * (z1 + 2.0f * yp[(size_t)r * 128 + 64 + lane]) + b[64 + lane];
  if (act) { v0 = (v0 >= 0.f) ? v0 : 0.01f * v0; v1 = (v1 >= 0.f) ? v1 : 0.01f * v1; }
  outf[(size_t)r * 128 + lane] = v0;
  outf[(size_t)r * 128 + 64 + lane] = v1;
  if (SCORE) {
    float w0 = w[lane], w1 = w[64 + lane];
    float nr = w0 * w0 + w1 * w1;
    float dt = v0 * w0 + v1 * w1;
    #pragma unroll
    for (int off = 32; off; off >>= 1) { nr += __shfl_down(nr, off); dt += __shfl_down(dt, off); }
    if (lane == 0) ts[r] = tanhf(dt / sqrtf(nr));
  }
}

// ---------------- top-k rank select ----------------
__global__ __launch_bounds__(256) void k_rank(const float* __restrict__ ts, int n, int k,
                                              int* __restrict__ perm, int* __restrict__ inv) {
  int wave = threadIdx.x >> 6, lane = threadIdx.x & 63;
  int i = blockIdx.x * 4 + wave;
  if (i >= n) return;
  unsigned bits = __float_as_uint(ts[i]);
  unsigned u = (bits & 0x80000000u) ? ~bits : (bits | 0x80000000u);
  unsigned long long my = ((unsigned long long)u << 32) | (unsigned)(0xFFFFFFFFu - (unsigned)i);
  int rank = 0;
  for (int j = lane; j < n; j += 64) {
    unsigned b2 = __float_as_uint(ts[j]);
    unsigned u2 = (b2 & 0x80000000u) ? ~b2 : (b2 | 0x80000000u);
    unsigned long long kj = ((unsigned long long)u2 << 32) | (unsigned)(0xFFFFFFFFu - (unsigned)j);
    rank += (kj > my) ? 1 : 0;
  }
  #pragma unroll
  for (int off = 32; off; off >>= 1) rank += __shfl_down(rank, off);
  if (lane == 0) {
    if (rank < k) perm[rank] = i;
    inv[i] = (rank < k) ? rank : -1;
  }
}

// ---------------- dense augment for L2/L3 ----------------
__global__ __launch_bounds__(256) void k_prep(const float* __restrict__ A, u16* __restrict__ A1,
                                              u16* __restrict__ A1T, int n) {
  __shared__ float tile[32][33];
  int bi = blockIdx.y, bj = blockIdx.x;
  int tx = threadIdx.x & 31, ty = threadIdx.x >> 5;
  int r0 = bi * 32, c0 = bj * 32;
  #pragma unroll
  for (int yy = 0; yy < 4; ++yy) {
    int r = ty * 4 + yy;
    int gr = r0 + r, gc = c0 + tx;
    float v = A[(size_t)gr * n + gc];
    if (gr == gc) v = 1.0f;
    tile[r][tx] = v;
    A1[(size_t)gr * n + gc] = f2bf_(v);
  }
  __syncthreads();
  #pragma unroll
  for (int yy = 0; yy < 4; ++yy) {
    int r = ty * 4 + yy;
    int gr = c0 + r, gc = r0 + tx;
    A1T[(size_t)gr * n + gc] = f2bf_(tile[tx][r]);
  }
}

// dense pool (L2/L3): split-K atomicAdd (exact integers); diag skipped (stays 0 from fill)
__global__ __launch_bounds__(256) void k_mfma_pool(const u16* __restrict__ A1, const u16* __restrict__ A1T,
                                                   const int* __restrict__ perm, float* __restrict__ C,
                                                   int M, int K, int kchunk) {
  __shared__ __align__(16) u16 a_lds[128 * 64];
  __shared__ __align__(16) u16 b_lds[128 * 64];
  __shared__ int pr[128], pc[128];
  int t = threadIdx.x;
  int br = blockIdx.x, bc = blockIdx.y;
  int kbase = blockIdx.z * kchunk;
  if (t < 128) pr[t] = perm[br * 128 + t];
  else pc[t - 128] = perm[bc * 128 + (t - 128)];
  __syncthreads();
  int wave = t >> 6, lane = t & 63;
  int wr = wave >> 1, wc = wave & 1;
  int lrow = lane & 15, kb = lane >> 4;
  const f32x4 z4 = {0.f, 0.f, 0.f, 0.f};
  f32x4 acc[4][4];
  #pragma unroll
  for (int a = 0; a < 4; ++a)
    #pragma unroll
    for (int b = 0; b < 4; ++b) acc[a][b] = z4;

  for (int k0 = 0; k0 < kchunk; k0 += 64) {
    int koff = kbase + k0;
    __syncthreads();
    #pragma unroll
    for (int it = 0; it < 4; ++it) {
      int q = it * 256 + t;
      int r = q >> 3, g = q & 7;
      int ld = r * 64 + ((g ^ (r & 7)) << 3);
      *(s16x8*)&a_lds[ld] = *(const s16x8*)(A1 + (size_t)pr[r] * K + koff + g * 8);
      *(s16x8*)&b_lds[ld] = *(const s16x8*)(A1T + (size_t)pc[r] * K + koff + g * 8);
    }
    __syncthreads();
    #pragma unroll
    for (int ks = 0; ks < 2; ++ks) {
      int gg = ks * 4 + kb;
      int gsw = (gg ^ (lrow & 7)) << 3;
      s16x8 af[4], bfv[4];
      #pragma unroll
      for (int mi = 0; mi < 4; ++mi)
        af[mi] = *(const s16x8*)&a_lds[(wr * 64 + mi * 16 + lrow) * 64 + gsw];
      #pragma unroll
      for (int ni = 0; ni < 4; ++ni)
        bfv[ni] = *(const s16x8*)&b_lds[(wc * 64 + ni * 16 + lrow) * 64 + gsw];
      #pragma unroll
      for (int mi = 0; mi < 4; ++mi)
        #pragma unroll
        for (int ni = 0; ni < 4; ++ni)
          acc[mi][ni] = __builtin_amdgcn_mfma_f32_16x16x32_bf16(af[mi], bfv[ni], acc[mi][ni], 0, 0, 0);
    }
  }
  int rbase = (lane >> 4) * 4;
  #pragma unroll
  for (int mi = 0; mi < 4; ++mi)
    #pragma unroll
    for (int ni = 0; ni < 4; ++ni)
      #pragma unroll
      for (int j = 0; j < 4; ++j) {
        int gi = br * 128 + wr * 64 + mi * 16 + rbase + j;
        int gj = bc * 128 + wc * 64 + ni * 16 + (lane & 15);
        if (gi != gj) atomicAdd(&C[(size_t)gi * M + gj], acc[mi][ni][j]);
      }
}

// ---------------- driver ----------------
extern "C" void kernel_launch(void* const* d_in, const int* in_sizes, int n_in,
                              void* d_out, int out_size, void* d_ws, size_t ws_size,
                              hipStream_t stream) {
  (void)in_sizes; (void)n_in; (void)out_size; (void)ws_size;
  const void* x_in  = d_in[0];
  const int*  ei    = (const int*)d_in[1];
  const void* Wd_in = d_in[2];
  const void* bd_in = d_in[3];
  const void* Wu_in = d_in[4];
  const void* bu_in = d_in[5];
  const void* pw_in = d_in[6];

  char* p = (char*)d_ws;
  auto alloc = [&](size_t bytes) { char* r = p; p += (bytes + 255) & ~(size_t)255; return r; };
  float* A1p  = (float*)alloc(2048ull * 2048 * 4);
  float* A2p  = (float*)alloc(1024ull * 1024 * 4);
  float* A3p  = (float*)alloc(512ull * 512 * 4);
  u16*   A1b  = (u16*)alloc(4096ull * 4096 * 2);   // L2/L3 pool src; zpart aliases during GCNs
  u16*   A1bT = (u16*)alloc(4096ull * 4096 * 2);   // L2/L3 pool src^T; yTh/yTl alias during GCNs
  float* xb0  = (float*)alloc(4096 * 128 * 4);
  float* xb1  = (float*)alloc(2048 * 128 * 4);
  float* xb2  = (float*)alloc(1024 * 128 * 4);
  float* xb3  = (float*)alloc(512 * 128 * 4);
  float* xin  = (float*)alloc(4096 * 128 * 4);
  float* tmpY = (float*)alloc(4096 * 128 * 4);
  float* dinv0 = (float*)alloc(4096 * 4);
  float* dinv1 = (float*)alloc(2048 * 4);
  float* dinv2 = (float*)alloc(1024 * 4);
  float* dinv3 = (float*)alloc(512 * 4);
  float* tsc  = (float*)alloc(4096 * 4);
  float* Wdf  = (float*)alloc(4 * 128 * 128 * 4);
  float* bdf  = (float*)alloc(4 * 128 * 4);
  float* Wuf  = (float*)alloc(3 * 128 * 128 * 4);
  float* buf_ = (float*)alloc(3 * 128 * 4);
  float* pwf  = (float*)alloc(3 * 128 * 4);
  int* iblk = (int*)alloc((12292 + 3 * 4097 + 3 * 4096 + 4 * 65536 + 4096 + 2048 + 1024 + 2048 + 1024 + 512) * 4);
  int* flags  = iblk;
  int* indeg  = iblk + 4;
  int* outdeg = iblk + 4100;
  int* indeg2 = iblk + 8196;
  int* q      = iblk + 12292;
  int* inoff  = q;  q += 4097;
  int* outoff = q;  q += 4097;
  int* inoff2 = q;  q += 4097;
  int* incur  = q;  q += 4096;
  int* outcur = q;  q += 4096;
  int* incur2 = q;  q += 4096;
  int* inlist = q;  q += 65536;
  int* outlist= q;  q += 65536;
  int* inlist2= q;  q += 65536;
  int* inlist2s = q; q += 65536;
  int* inv1   = q;  q += 4096;
  int* inv2   = q;  q += 2048;
  int* inv3   = q;  q += 1024;
  int* perm1  = q;  q += 2048;
  int* perm2  = q;  q += 1024;
  int* perm3  = q;  q += 512;

  float* zpart = (float*)A1b;
  u16*   yTh   = (u16*)A1bT;
  u16*   yTl   = (u16*)A1bT + 128 * 4096;

  const int E = 65536, N0 = 4096;

  // setup
  k_zeroi<<<(12292 + 255) / 256, 256, 0, stream>>>(iblk, 12292);
  k_detect<<<16, 256, 0, stream>>>((const u16*)x_in, ei, flags);
  k_loadall<<<(640256 + 255) / 256, 256, 0, stream>>>(x_in, Wd_in, bd_in, Wu_in, bu_in, pw_in,
                                                      xin, Wdf, bdf, Wuf, buf_, pwf, flags);
  k_degcnt<<<(E + 255) / 256, 256, 0, stream>>>(ei, E, N0, flags, indeg, outdeg, indeg2);
  k_scan3<<<1, 1024, 0, stream>>>(indeg, outdeg, indeg2, inoff, outoff, inoff2,
                                  incur, outcur, incur2, N0);
  k_csrfill<<<(E + 255) / 256, 256, 0, stream>>>(ei, E, N0, flags, incur, outcur, incur2,
                                                 inlist, outlist, inlist2);
  k_rowsort<<<N0 / 4, 256, 0, stream>>>(inoff2, inlist2, inlist2s, indeg2, dinv0, N0);

  // level-0 GCN (sparse, fused) + score for L1 pool
  k_xw<0, 0, 0><<<N0 / 16, 256, 0, stream>>>(xin, nullptr, nullptr, nullptr, nullptr, nullptr,
                                             nullptr, Wdf, dinv0, tmpY, nullptr, nullptr, N0);
  k_spmv<0, 1><<<N0 / 4, 256, 0, stream>>>(inoff2, inlist2s, tmpY, dinv0, bdf, pwf,
                                           xb0, nullptr, tsc, N0, 1, flags);

  // ---- level 1: sparse pool + dense GCN(2048) ----
  {
    int n = 4096, k = 2048;
    k_rank<<<n / 4, 256, 0, stream>>>(tsc, n, k, perm1, inv1);
    k_fill0<<<2048, 256, 0, stream>>>((float4*)A1p, (long)k * k / 4);
    int njoin = n / 4;
    k_spool<<<njoin + (E + 255) / 256, 256, 0, stream>>>(inoff, inlist, outoff, outlist, inv1, A1p,
                                                         k, n, njoin, ei, E, flags);
    k_xw<1, 1, 1><<<k / 16, 256, 0, stream>>>(xb0, nullptr, nullptr, perm1, nullptr, tsc,
                                              A1p, Wdf + 16384, dinv1, tmpY, yTh, yTl, k);
    k_zgemm_mfma<0><<<dim3(k / 128, 16), 256, 0, stream>>>(A1p, yTh, yTl, zpart, k, k / 16);
    k_epi<1><<<k / 4, 256, 0, stream>>>(zpart, tmpY, dinv1, bdf + 128, pwf + 128, xb1, tsc, k, 16, 1);
  }

  // ---- levels 2,3: dense MFMA pool + dense GCN ----
  {
    float* Acurs[2]  = {A1p, A2p};
    float* Anexts[2] = {A2p, A3p};
    int*   perms[2]  = {perm2, perm3};
    int*   invs[2]   = {inv2, inv3};
    float* xcurs[2]  = {xb1, xb2};
    float* xouts[2]  = {xb2, xb3};
    float* dinvs[2]  = {dinv2, dinv3};
    int    spoolS[2] = {4, 8};
    int    ns[2]     = {2048, 1024};
    for (int li = 0; li < 2; ++li) {
      int n = ns[li], k = n / 2, lvl = li + 2;
      k_rank<<<n / 4, 256, 0, stream>>>(tsc, n, k, perms[li], invs[li]);
      k_prep<<<dim3(n / 32, n / 32), 256, 0, stream>>>(Acurs[li], A1b, A1bT, n);
      float* Cn = Anexts[li];
      int Sp = spoolS[li];
      k_fill0<<<2048, 256, 0, stream>>>((float4*)Cn, (long)k * k / 4);
      k_mfma_pool<<<dim3(k / 128, k / 128, Sp), 256, 0, stream>>>(A1b, A1bT, perms[li], Cn, k, n, n / Sp);
      int S = (k >= 2048) ? 16 : (k == 1024 ? 8 : 4);
      k_xw<1, 1, 1><<<k / 16, 256, 0, stream>>>(xcurs[li], nullptr, nullptr, perms[li], nullptr, tsc,
                                                Cn, Wdf + lvl * 16384, dinvs[li], tmpY, yTh, yTl, k);
      k_zgemm_mfma<1><<<dim3(k / 128, S), 256, 0, stream>>>(Cn, yTh, yTl, zpart, k, k / S);
      if (li == 0)
        k_epi<1><<<k / 4, 256, 0, stream>>>(zpart, tmpY, dinvs[li], bdf + lvl * 128, pwf + lvl * 128,
                                            xouts[li], tsc, k, S, 1);
      else
        k_epi<0><<<k / 4, 256, 0, stream>>>(zpart, tmpY, dinvs[li], bdf + lvl * 128, nullptr,
                                            xouts[li], nullptr, k, S, 1);
    }
  }

  // ---- up path (dinv cached; unpool fused into xw) ----
  // up1: n=1024, A2p (alo=1)
  k_xw<2, 0, 1><<<1024 / 16, 256, 0, stream>>>(nullptr, xb2, xb3, nullptr, inv3, nullptr,
                                               nullptr, Wuf, dinv2, tmpY, yTh, yTl, 1024);
  k_zgemm_mfma<1><<<dim3(1024 / 128, 8), 256, 0, stream>>>(A2p, yTh, yTl, zpart, 1024, 1024 / 8);
  k_epi<0><<<1024 / 4, 256, 0, stream>>>(zpart, tmpY, dinv2, buf_, nullptr, xb2, nullptr, 1024, 8, 1);

  // up2: n=2048, A1p (alo=0)
  k_xw<2, 0, 1><<<2048 / 16, 256, 0, stream>>>(nullptr, xb1, xb2, nullptr, inv2, nullptr,
                                               nullptr, Wuf + 16384, dinv1, tmpY, yTh, yTl, 2048);
  k_zgemm_mfma<0><<<dim3(2048 / 128, 16), 256, 0, stream>>>(A1p, yTh, yTl, zpart, 2048, 2048 / 16);
  k_epi<0><<<2048 / 4, 256, 0, stream>>>(zpart, tmpY, dinv1, buf_ + 128, nullptr, xb1, nullptr, 2048, 16, 1);

  // up3: n=4096, sparse A0, final output (no act)
  k_xw<2, 0, 0><<<N0 / 16, 256, 0, stream>>>(nullptr, xb0, xb1, nullptr, inv1, nullptr,
                                             nullptr, Wuf + 2 * 16384, dinv0, tmpY, nullptr, nullptr, N0);
  k_spmv<1, 0><<<N0 / 4, 256, 0, stream>>>(inoff2, inlist2s, tmpY, dinv0, buf_ + 2 * 128, nullptr,
                                           nullptr, d_out, nullptr, N0, 0, flags);
}

// Round 10
// 363.599 us; speedup vs baseline: 1.1280x; 1.1280x over previous
//
#include <hip/hip_runtime.h>

typedef unsigned short u16;
typedef __attribute__((ext_vector_type(4))) short s16x4;
typedef __attribute__((ext_vector_type(8))) short s16x8;
typedef __attribute__((ext_vector_type(4))) float f32x4;

__device__ __forceinline__ float bf2f_(u16 b) { return __uint_as_float(((unsigned)b) << 16); }
__device__ __forceinline__ u16 f2bf_(float f) {
  unsigned u = __float_as_uint(f);
  return (u16)((u + 0x7FFFu + ((u >> 16) & 1u)) >> 16);
}

__device__ __forceinline__ void edge_decode(const int* ei, int e, int E, const int* flags,
                                            int& src, int& dst) {
  bool is64 = flags[1] < 100;
  src = is64 ? ei[2 * e] : ei[e];
  dst = is64 ? ei[2 * E + 2 * e] : ei[E + e];
}

// ---------------- setup ----------------
__global__ void k_zeroi(int* a, int n) {
  int i = blockIdx.x * 256 + threadIdx.x;
  if (i < n) a[i] = 0;
}

__global__ __launch_bounds__(256) void k_detect(const u16* __restrict__ xb,
                                                const int* __restrict__ ei,
                                                int* __restrict__ flags) {
  int i = blockIdx.x * 256 + threadIdx.x;  // 4096 threads
  int e8 = (xb[2 * i] >> 7) & 0xFF;
  int sane = (e8 >= 100 && e8 <= 140) ? 1 : 0;
  int nz = (ei[2 * i + 1] != 0) ? 1 : 0;
  #pragma unroll
  for (int off = 32; off; off >>= 1) { sane += __shfl_down(sane, off); nz += __shfl_down(nz, off); }
  if ((threadIdx.x & 63) == 0) { atomicAdd(&flags[0], sane); atomicAdd(&flags[1], nz); }
}

__global__ void k_loadall(const void* x, const void* wd, const void* bd, const void* wu,
                          const void* bu, const void* pw,
                          float* xin, float* Wdf, float* bdf, float* Wuf, float* buf_, float* pwf,
                          const int* __restrict__ flags) {
  int i = blockIdx.x * 256 + threadIdx.x;
  const void* src; float* dst; int off;
  if (i < 524288) { src = x; dst = xin; off = i; }
  else if (i < 589824) { src = wd; dst = Wdf; off = i - 524288; }
  else if (i < 590336) { src = bd; dst = bdf; off = i - 589824; }
  else if (i < 639488) { src = wu; dst = Wuf; off = i - 590336; }
  else if (i < 639872) { src = bu; dst = buf_; off = i - 639488; }
  else if (i < 640256) { src = pw; dst = pwf; off = i - 639872; }
  else return;
  bool isbf = flags[0] >= 2048;
  dst[off] = isbf ? bf2f_(((const u16*)src)[off]) : ((const float*)src)[off];
}

__global__ void k_fill0(float4* __restrict__ p, long n4) {
  long i = blockIdx.x * 256L + threadIdx.x;
  long stride = (long)gridDim.x * 256L;
  for (; i < n4; i += stride) p[i] = make_float4(0.f, 0.f, 0.f, 0.f);
}

// ---------------- CSR build ----------------
__global__ void k_degcnt(const int* __restrict__ ei, int E, int n, const int* __restrict__ flags,
                         int* __restrict__ indeg, int* __restrict__ outdeg, int* __restrict__ indeg2) {
  int e = blockIdx.x * 256 + threadIdx.x;
  if (e >= E) return;
  int src, dst; edge_decode(ei, e, E, flags, src, dst);
  if (src < 0 || src >= n || dst < 0 || dst >= n) return;
  atomicAdd(&indeg2[dst], 1);
  if (src == dst) return;
  atomicAdd(&indeg[dst], 1);
  atomicAdd(&outdeg[src], 1);
}

__global__ __launch_bounds__(1024) void k_scan3(const int* __restrict__ d0, const int* __restrict__ d1,
                                                const int* __restrict__ d2,
                                                int* o0, int* o1, int* o2,
                                                int* c0, int* c1, int* c2, int n) {
  __shared__ int part[1024];
  int t = threadIdx.x;
  int per = n / 1024;
  for (int pass = 0; pass < 3; ++pass) {
    const int* deg = pass == 0 ? d0 : (pass == 1 ? d1 : d2);
    int* off = pass == 0 ? o0 : (pass == 1 ? o1 : o2);
    int* cur = pass == 0 ? c0 : (pass == 1 ? c1 : c2);
    int local[8];
    int s = 0;
    for (int j = 0; j < per; ++j) { local[j] = s; s += deg[t * per + j]; }
    part[t] = s;
    __syncthreads();
    for (int d = 1; d < 1024; d <<= 1) {
      int v = (t >= d) ? part[t - d] : 0;
      __syncthreads();
      part[t] += v;
      __syncthreads();
    }
    int base = (t == 0) ? 0 : part[t - 1];
    for (int j = 0; j < per; ++j) {
      off[t * per + j] = base + local[j];
      cur[t * per + j] = base + local[j];
    }
    if (t == 1023) off[n] = part[1023];
    __syncthreads();
  }
}

__global__ void k_csrfill(const int* __restrict__ ei, int E, int n, const int* __restrict__ flags,
                          int* __restrict__ incur, int* __restrict__ outcur, int* __restrict__ incur2,
                          int* __restrict__ inlist, int* __restrict__ outlist, int* __restrict__ inlist2) {
  int e = blockIdx.x * 256 + threadIdx.x;
  if (e >= E) return;
  int src, dst; edge_decode(ei, e, E, flags, src, dst);
  if (src < 0 || src >= n || dst < 0 || dst >= n) return;
  inlist2[atomicAdd(&incur2[dst], 1)] = src;
  if (src == dst) return;
  inlist[atomicAdd(&incur[dst], 1)] = src;
  outlist[atomicAdd(&outcur[src], 1)] = dst;
}

// wave-parallel row sort (deterministic contents) + dinv0 from counts
__global__ __launch_bounds__(256) void k_rowsort(const int* __restrict__ inoff2,
                                                 const int* __restrict__ inlist2,
                                                 int* __restrict__ outlist2,
                                                 const int* __restrict__ indeg2,
                                                 float* __restrict__ dinv, int n) {
  int wave = threadIdx.x >> 6, lane = threadIdx.x & 63;
  int row = blockIdx.x * 4 + wave;
  if (row >= n) return;
  int ib = inoff2[row], ie = inoff2[row + 1];
  int L = ie - ib;
  for (int i = lane; i < L; i += 64) {
    int ki = inlist2[ib + i];
    int rank = 0;
    for (int j = 0; j < L; ++j) {
      int kj = inlist2[ib + j];
      rank += (kj < ki || (kj == ki && j < i)) ? 1 : 0;
    }
    outlist2[ib + rank] = ki;
  }
  if (lane == 0) dinv[row] = rsqrtf((float)indeg2[row] + 2.0f);
}

// ---------------- sparse L1 pool (join + 2*Ao edge term in one kernel) ----------------
__global__ __launch_bounds__(256) void k_spool(const int* __restrict__ inoff, const int* __restrict__ inlist,
                                               const int* __restrict__ outoff, const int* __restrict__ outlist,
                                               const int* __restrict__ inv, float* __restrict__ C,
                                               int M, int n, int njoin,
                                               const int* __restrict__ ei, int E, const int* __restrict__ flags) {
  int wave = threadIdx.x >> 6, lane = threadIdx.x & 63;
  if ((int)blockIdx.x < njoin) {
    int v = blockIdx.x * 4 + wave;
    if (v >= n) return;
    int ib = inoff[v], ni = inoff[v + 1] - ib;
    int ob = outoff[v], no = outoff[v + 1] - ob;
    int tot = ni * no;
    for (int p = lane; p < tot; p += 64) {
      int oi = p / ni, ii = p - oi * ni;
      int i = outlist[ob + oi];
      int j = inlist[ib + ii];
      if (i == j) continue;
      int ri = inv[i], rj = inv[j];
      if (ri >= 0 && rj >= 0) atomicAdd(&C[(size_t)ri * M + rj], 1.0f);
    }
  } else {
    int e = (blockIdx.x - njoin) * 256 + threadIdx.x;
    if (e >= E) return;
    int src, dst; edge_decode(ei, e, E, flags, src, dst);
    if (src < 0 || src >= n || dst < 0 || dst >= n || src == dst) return;
    int ri = inv[dst], rj = inv[src];
    if (ri >= 0 && rj >= 0) atomicAdd(&C[(size_t)ri * M + rj], 2.0f);
  }
}

// ---------------- dedicated dinv (full-grid rowsum; one block per row) ----------------
__global__ __launch_bounds__(256) void k_dinv(const float* __restrict__ A, float* __restrict__ dinv, int n) {
  int row = blockIdx.x;
  const float* r = A + (size_t)row * n;
  float s = 0.f;
  for (int j = threadIdx.x; j < n; j += 256) s += r[j];
  #pragma unroll
  for (int off = 32; off; off >>= 1) s += __shfl_down(s, off);
  __shared__ float red[4];
  int wave = threadIdx.x >> 6, lane = threadIdx.x & 63;
  if (lane == 0) red[wave] = s;
  __syncthreads();
  if (threadIdx.x == 0) {
    float deg = red[0] + red[1] + red[2] + red[3] + 2.0f;
    dinv[row] = rsqrtf(deg);
  }
}

// ---------------- fused xW kernel ----------------
// MODE: 0 plain x, 1 gather (x[perm[r]]*ts), 2 unpool (res[r]+prev[inv[r]])
// WT: 1 -> also write yTh/yTl bf16 hi/lo transpose chunks. dinv always read cached.
template<int MODE, int WT>
__global__ __launch_bounds__(256) void k_xw(const float* __restrict__ x, const float* __restrict__ res,
                                            const float* __restrict__ prev,
                                            const int* __restrict__ perm, const int* __restrict__ invm,
                                            const float* __restrict__ ts,
                                            const float* __restrict__ W,
                                            const float* __restrict__ dinv, float* __restrict__ yp,
                                            u16* __restrict__ yTh, u16* __restrict__ yTl, int n) {
  __shared__ float xs_[16 * 128];
  __shared__ float ds[16];
  int t = threadIdx.x;
  int row0 = blockIdx.x * 16;
  for (int e = t; e < 16 * 128; e += 256) {
    int r = e >> 7, c = e & 127;
    int gr = row0 + r;
    float v;
    if (MODE == 0) v = x[(size_t)gr * 128 + c];
    else if (MODE == 1) { int p0 = perm[gr]; v = x[(size_t)p0 * 128 + c] * ts[p0]; }
    else {
      int ir = invm[gr];
      v = res[(size_t)gr * 128 + c];
      if (ir >= 0) v += prev[(size_t)ir * 128 + c];
    }
    xs_[e] = v;
  }
  if (t < 16) ds[t] = dinv[row0 + t];
  __syncthreads();
  int c = t & 127, rh = t >> 7;
  float acc[8];
  #pragma unroll
  for (int ri = 0; ri < 8; ++ri) acc[ri] = 0.f;
  for (int k = 0; k < 128; ++k) {
    float wv = W[k * 128 + c];
    #pragma unroll
    for (int ri = 0; ri < 8; ++ri) acc[ri] += xs_[(rh * 8 + ri) * 128 + k] * wv;
  }
  s16x8 h, l;
  #pragma unroll
  for (int ri = 0; ri < 8; ++ri) {
    int r = row0 + rh * 8 + ri;
    float v = ds[rh * 8 + ri] * acc[ri];
    yp[(size_t)r * 128 + c] = v;
    if (WT) {
      u16 hb = f2bf_(v);
      h[ri] = (short)hb;
      l[ri] = (short)f2bf_(v - bf2f_(hb));
    }
  }
  if (WT) {
    int rbase = row0 + rh * 8;
    *(s16x8*)&yTh[(size_t)c * n + rbase] = h;
    *(s16x8*)&yTl[(size_t)c * n + rbase] = l;
  }
}

// ---------------- fused CSR SpMV + GCN epilogue (+optional score) ----------------
template<int FINAL, int SCORE>
__global__ __launch_bounds__(256) void k_spmv(const int* __restrict__ inoff2, const int* __restrict__ inlist2,
                                              const float* __restrict__ y, const float* __restrict__ dinv,
                                              const float* __restrict__ b, const float* __restrict__ w,
                                              float* __restrict__ outf, void* __restrict__ outv,
                                              float* __restrict__ ts,
                                              int n, int act, const int* __restrict__ flags) {
  int wave = threadIdx.x >> 6, lane = threadIdx.x & 63;
  int i = blockIdx.x * 4 + wave;
  if (i >= n) return;
  int ib = inoff2[i], ie = inoff2[i + 1];
  float z0 = 0.f, z1 = 0.f;
  for (int e = ib; e < ie; ++e) {
    int s = inlist2[e];
    z0 += y[(size_t)s * 128 + lane];
    z1 += y[(size_t)s * 128 + 64 + lane];
  }
  float di = dinv[i];
  float y0 = y[(size_t)i * 128 + lane], y1 = y[(size_t)i * 128 + 64 + lane];
  float v0 = di * (z0 + 2.0f * y0) + b[lane];
  float v1 = di * (z1 + 2.0f * y1) + b[64 + lane];
  if (act) { v0 = (v0 >= 0.f) ? v0 : 0.01f * v0; v1 = (v1 >= 0.f) ? v1 : 0.01f * v1; }
  if (FINAL) {
    if (flags[0] >= 2048) {
      ((u16*)outv)[(size_t)i * 128 + lane] = f2bf_(v0);
      ((u16*)outv)[(size_t)i * 128 + 64 + lane] = f2bf_(v1);
    } else {
      ((float*)outv)[(size_t)i * 128 + lane] = v0;
      ((float*)outv)[(size_t)i * 128 + 64 + lane] = v1;
    }
  } else {
    outf[(size_t)i * 128 + lane] = v0;
    outf[(size_t)i * 128 + 64 + lane] = v1;
  }
  if (SCORE) {
    float w0 = w[lane], w1 = w[64 + lane];
    float nr = w0 * w0 + w1 * w1;
    float dt = v0 * w0 + v1 * w1;
    #pragma unroll
    for (int off = 32; off; off >>= 1) { nr += __shfl_down(nr, off); dt += __shfl_down(dt, off); }
    if (lane == 0) ts[i] = tanhf(dt / sqrtf(nr));
  }
}

// ---------------- dense zgemm (n<=2048) ----------------
template<int ALO>
__global__ __launch_bounds__(256) void k_zgemm_mfma(const float* __restrict__ A,
                                                    const u16* __restrict__ yTh,
                                                    const u16* __restrict__ yTl,
                                                    float* __restrict__ zpart,
                                                    int n, int kchunk) {
  __shared__ __align__(16) u16 ah_[128 * 64];
  __shared__ __align__(16) u16 al_[ALO ? 128 * 64 : 8];
  __shared__ __align__(16) u16 bh_[128 * 64];
  __shared__ __align__(16) u16 bl_[128 * 64];
  int t = threadIdx.x;
  int row0 = blockIdx.x * 128;
  int s = blockIdx.y;
  int kbase = s * kchunk;
  int wave = t >> 6, lane = t & 63;
  int wr = wave >> 1, wc = wave & 1;
  int lrow = lane & 15, kb = lane >> 4;
  const f32x4 z4 = {0.f, 0.f, 0.f, 0.f};
  f32x4 acc[4][4];
  #pragma unroll
  for (int a = 0; a < 4; ++a)
    #pragma unroll
    for (int b = 0; b < 4; ++b) acc[a][b] = z4;

  for (int k0 = 0; k0 < kchunk; k0 += 64) {
    int koff = kbase + k0;
    __syncthreads();
    #pragma unroll
    for (int it = 0; it < 8; ++it) {
      int q = it * 256 + t;
      int r = q >> 4, i4 = q & 15;
      int g = i4 >> 1, h4 = (i4 & 1) * 4;
      float4 v = *(const float4*)&A[(size_t)(row0 + r) * n + koff + i4 * 4];
      float vv[4] = {v.x, v.y, v.z, v.w};
      s16x4 hh, ll;
      #pragma unroll
      for (int j = 0; j < 4; ++j) {
        u16 hb = f2bf_(vv[j]);
        hh[j] = (short)hb;
        if (ALO) ll[j] = (short)f2bf_(vv[j] - bf2f_(hb));
      }
      int ld = r * 64 + ((g ^ (r & 7)) << 3) + h4;
      *(s16x4*)&ah_[ld] = hh;
      if (ALO) *(s16x4*)&al_[ld] = ll;
    }
    #pragma unroll
    for (int it = 0; it < 4; ++it) {
      int q = it * 256 + t;
      int r = q >> 3, g = q & 7;
      int ld = r * 64 + ((g ^ (r & 7)) << 3);
      *(s16x8*)&bh_[ld] = *(const s16x8*)(yTh + (size_t)r * n + koff + g * 8);
      *(s16x8*)&bl_[ld] = *(const s16x8*)(yTl + (size_t)r * n + koff + g * 8);
    }
    __syncthreads();
    #pragma unroll
    for (int ks = 0; ks < 2; ++ks) {
      int gg = ks * 4 + kb;
      int gsw = (gg ^ (lrow & 7)) << 3;
      s16x8 af[4], alf[4], bhf[4], blf[4];
      #pragma unroll
      for (int mi = 0; mi < 4; ++mi) {
        int row = wr * 64 + mi * 16 + lrow;
        af[mi] = *(const s16x8*)&ah_[row * 64 + gsw];
        if (ALO) alf[mi] = *(const s16x8*)&al_[row * 64 + gsw];
      }
      #pragma unroll
      for (int ni = 0; ni < 4; ++ni) {
        int row = wc * 64 + ni * 16 + lrow;
        bhf[ni] = *(const s16x8*)&bh_[row * 64 + gsw];
        blf[ni] = *(const s16x8*)&bl_[row * 64 + gsw];
      }
      #pragma unroll
      for (int mi = 0; mi < 4; ++mi)
        #pragma unroll
        for (int ni = 0; ni < 4; ++ni) {
          acc[mi][ni] = __builtin_amdgcn_mfma_f32_16x16x32_bf16(af[mi], bhf[ni], acc[mi][ni], 0, 0, 0);
          acc[mi][ni] = __builtin_amdgcn_mfma_f32_16x16x32_bf16(af[mi], blf[ni], acc[mi][ni], 0, 0, 0);
          if (ALO) {
            acc[mi][ni] = __builtin_amdgcn_mfma_f32_16x16x32_bf16(alf[mi], bhf[ni], acc[mi][ni], 0, 0, 0);
            acc[mi][ni] = __builtin_amdgcn_mfma_f32_16x16x32_bf16(alf[mi], blf[ni], acc[mi][ni], 0, 0, 0);
          }
        }
    }
  }
  int rbase = (lane >> 4) * 4;
  #pragma unroll
  for (int mi = 0; mi < 4; ++mi)
    #pragma unroll
    for (int ni = 0; ni < 4; ++ni)
      #pragma unroll
      for (int j = 0; j < 4; ++j) {
        int gi = row0 + wr * 64 + mi * 16 + rbase + j;
        int gj = wc * 64 + ni * 16 + (lane & 15);
        zpart[((size_t)s * n + gi) * 128 + gj] = acc[mi][ni][j];
      }
}

// row-per-wave epilogue: v = dinv*(sum_s zpart + 2*yp) + b; leaky; optional score
template<int SCORE>
__global__ __launch_bounds__(256) void k_epi(const float* __restrict__ zpart, const float* __restrict__ yp,
                                             const float* __restrict__ dinv, const float* __restrict__ b,
                                             const float* __restrict__ w,
                                             float* __restrict__ outf, float* __restrict__ ts,
                                             int n, int S, int act) {
  int wave = threadIdx.x >> 6, lane = threadIdx.x & 63;
  int r = blockIdx.x * 4 + wave;
  if (r >= n) return;
  float z0 = 0.f, z1 = 0.f;
  for (int s = 0; s < S; ++s) {
    const float* zp = zpart + ((size_t)s * n + r) * 128;
    z0 += zp[lane];
    z1 += zp[64 + lane];
  }
  float di = dinv[r];
  float v0 = di * (z0 + 2.0f * yp[(size_t)r * 128 + lane]) + b[lane];
  float v1 = di * (z1 + 2.0f * yp[(size_t)r * 128 + 64 + lane]) + b[64 + lane];
  if (act) { v0 = (v0 >= 0.f) ? v0 : 0.01f * v0; v1 = (v1 >= 0.f) ? v1 : 0.01f * v1; }
  outf[(size_t)r * 128 + lane] = v0;
  outf[(size_t)r * 128 + 64 + lane] = v1;
  if (SCORE) {
    float w0 = w[lane], w1 = w[64 + lane];
    float nr = w0 * w0 + w1 * w1;
    float dt = v0 * w0 + v1 * w1;
    #pragma unroll
    for (int off = 32; off; off >>= 1) { nr += __shfl_down(nr, off); dt += __shfl_down(dt, off); }
    if (lane == 0) ts[r] = tanhf(dt / sqrtf(nr));
  }
}

// ---------------- top-k rank select ----------------
__global__ __launch_bounds__(256) void k_rank(const float* __restrict__ ts, int n, int k,
                                              int* __restrict__ perm, int* __restrict__ inv) {
  int wave = threadIdx.x >> 6, lane = threadIdx.x & 63;
  int i = blockIdx.x * 4 + wave;
  if (i >= n) return;
  unsigned bits = __float_as_uint(ts[i]);
  unsigned u = (bits & 0x80000000u) ? ~bits : (bits | 0x80000000u);
  unsigned long long my = ((unsigned long long)u << 32) | (unsigned)(0xFFFFFFFFu - (unsigned)i);
  int rank = 0;
  for (int j = lane; j < n; j += 64) {
    unsigned b2 = __float_as_uint(ts[j]);
    unsigned u2 = (b2 & 0x80000000u) ? ~b2 : (b2 | 0x80000000u);
    unsigned long long kj = ((unsigned long long)u2 << 32) | (unsigned)(0xFFFFFFFFu - (unsigned)j);
    rank += (kj > my) ? 1 : 0;
  }
  #pragma unroll
  for (int off = 32; off; off >>= 1) rank += __shfl_down(rank, off);
  if (lane == 0) {
    if (rank < k) perm[rank] = i;
    inv[i] = (rank < k) ? rank : -1;
  }
}

// ---------------- dense augment for L2/L3 ----------------
__global__ __launch_bounds__(256) void k_prep(const float* __restrict__ A, u16* __restrict__ A1,
                                              u16* __restrict__ A1T, int n) {
  __shared__ float tile[32][33];
  int bi = blockIdx.y, bj = blockIdx.x;
  int tx = threadIdx.x & 31, ty = threadIdx.x >> 5;
  int r0 = bi * 32, c0 = bj * 32;
  #pragma unroll
  for (int yy = 0; yy < 4; ++yy) {
    int r = ty * 4 + yy;
    int gr = r0 + r, gc = c0 + tx;
    float v = A[(size_t)gr * n + gc];
    if (gr == gc) v = 1.0f;
    tile[r][tx] = v;
    A1[(size_t)gr * n + gc] = f2bf_(v);
  }
  __syncthreads();
  #pragma unroll
  for (int yy = 0; yy < 4; ++yy) {
    int r = ty * 4 + yy;
    int gr = c0 + r, gc = r0 + tx;
    A1T[(size_t)gr * n + gc] = f2bf_(tile[tx][r]);
  }
}

// dense pool (L2/L3): split-K atomicAdd (exact integers); diag skipped (stays 0 from fill)
__global__ __launch_bounds__(256) void k_mfma_pool(const u16* __restrict__ A1, const u16* __restrict__ A1T,
                                                   const int* __restrict__ perm, float* __restrict__ C,
                                                   int M, int K, int kchunk) {
  __shared__ __align__(16) u16 a_lds[128 * 64];
  __shared__ __align__(16) u16 b_lds[128 * 64];
  __shared__ int pr[128], pc[128];
  int t = threadIdx.x;
  int br = blockIdx.x, bc = blockIdx.y;
  int kbase = blockIdx.z * kchunk;
  if (t < 128) pr[t] = perm[br * 128 + t];
  else pc[t - 128] = perm[bc * 128 + (t - 128)];
  __syncthreads();
  int wave = t >> 6, lane = t & 63;
  int wr = wave >> 1, wc = wave & 1;
  int lrow = lane & 15, kb = lane >> 4;
  const f32x4 z4 = {0.f, 0.f, 0.f, 0.f};
  f32x4 acc[4][4];
  #pragma unroll
  for (int a = 0; a < 4; ++a)
    #pragma unroll
    for (int b = 0; b < 4; ++b) acc[a][b] = z4;

  for (int k0 = 0; k0 < kchunk; k0 += 64) {
    int koff = kbase + k0;
    __syncthreads();
    #pragma unroll
    for (int it = 0; it < 4; ++it) {
      int q = it * 256 + t;
      int r = q >> 3, g = q & 7;
      int ld = r * 64 + ((g ^ (r & 7)) << 3);
      *(s16x8*)&a_lds[ld] = *(const s16x8*)(A1 + (size_t)pr[r] * K + koff + g * 8);
      *(s16x8*)&b_lds[ld] = *(const s16x8*)(A1T + (size_t)pc[r] * K + koff + g * 8);
    }
    __syncthreads();
    #pragma unroll
    for (int ks = 0; ks < 2; ++ks) {
      int gg = ks * 4 + kb;
      int gsw = (gg ^ (lrow & 7)) << 3;
      s16x8 af[4], bfv[4];
      #pragma unroll
      for (int mi = 0; mi < 4; ++mi)
        af[mi] = *(const s16x8*)&a_lds[(wr * 64 + mi * 16 + lrow) * 64 + gsw];
      #pragma unroll
      for (int ni = 0; ni < 4; ++ni)
        bfv[ni] = *(const s16x8*)&b_lds[(wc * 64 + ni * 16 + lrow) * 64 + gsw];
      #pragma unroll
      for (int mi = 0; mi < 4; ++mi)
        #pragma unroll
        for (int ni = 0; ni < 4; ++ni)
          acc[mi][ni] = __builtin_amdgcn_mfma_f32_16x16x32_bf16(af[mi], bfv[ni], acc[mi][ni], 0, 0, 0);
    }
  }
  int rbase = (lane >> 4) * 4;
  #pragma unroll
  for (int mi = 0; mi < 4; ++mi)
    #pragma unroll
    for (int ni = 0; ni < 4; ++ni)
      #pragma unroll
      for (int j = 0; j < 4; ++j) {
        int gi = br * 128 + wr * 64 + mi * 16 + rbase + j;
        int gj = bc * 128 + wc * 64 + ni * 16 + (lane & 15);
        if (gi != gj) atomicAdd(&C[(size_t)gi * M + gj], acc[mi][ni][j]);
      }
}

// ---------------- driver ----------------
extern "C" void kernel_launch(void* const* d_in, const int* in_sizes, int n_in,
                              void* d_out, int out_size, void* d_ws, size_t ws_size,
                              hipStream_t stream) {
  (void)in_sizes; (void)n_in; (void)out_size; (void)ws_size;
  const void* x_in  = d_in[0];
  const int*  ei    = (const int*)d_in[1];
  const void* Wd_in = d_in[2];
  const void* bd_in = d_in[3];
  const void* Wu_in = d_in[4];
  const void* bu_in = d_in[5];
  const void* pw_in = d_in[6];

  char* p = (char*)d_ws;
  auto alloc = [&](size_t bytes) { char* r = p; p += (bytes + 255) & ~(size_t)255; return r; };
  float* A1p  = (float*)alloc(2048ull * 2048 * 4);
  float* A2p  = (float*)alloc(1024ull * 1024 * 4);
  float* A3p  = (float*)alloc(512ull * 512 * 4);
  u16*   A1b  = (u16*)alloc(4096ull * 4096 * 2);   // L2/L3 pool src; zpart aliases during GCNs
  u16*   A1bT = (u16*)alloc(4096ull * 4096 * 2);   // L2/L3 pool src^T; yTh/yTl alias during GCNs
  float* xb0  = (float*)alloc(4096 * 128 * 4);
  float* xb1  = (float*)alloc(2048 * 128 * 4);
  float* xb2  = (float*)alloc(1024 * 128 * 4);
  float* xb3  = (float*)alloc(512 * 128 * 4);
  float* xin  = (float*)alloc(4096 * 128 * 4);
  float* tmpY = (float*)alloc(4096 * 128 * 4);
  float* dinv0 = (float*)alloc(4096 * 4);
  float* dinv1 = (float*)alloc(2048 * 4);
  float* dinv2 = (float*)alloc(1024 * 4);
  float* dinv3 = (float*)alloc(512 * 4);
  float* tsc  = (float*)alloc(4096 * 4);
  float* Wdf  = (float*)alloc(4 * 128 * 128 * 4);
  float* bdf  = (float*)alloc(4 * 128 * 4);
  float* Wuf  = (float*)alloc(3 * 128 * 128 * 4);
  float* buf_ = (float*)alloc(3 * 128 * 4);
  float* pwf  = (float*)alloc(3 * 128 * 4);
  int* iblk = (int*)alloc((12292 + 3 * 4097 + 3 * 4096 + 4 * 65536 + 4096 + 2048 + 1024 + 2048 + 1024 + 512) * 4);
  int* flags  = iblk;
  int* indeg  = iblk + 4;
  int* outdeg = iblk + 4100;
  int* indeg2 = iblk + 8196;
  int* q      = iblk + 12292;
  int* inoff  = q;  q += 4097;
  int* outoff = q;  q += 4097;
  int* inoff2 = q;  q += 4097;
  int* incur  = q;  q += 4096;
  int* outcur = q;  q += 4096;
  int* incur2 = q;  q += 4096;
  int* inlist = q;  q += 65536;
  int* outlist= q;  q += 65536;
  int* inlist2= q;  q += 65536;
  int* inlist2s = q; q += 65536;
  int* inv1   = q;  q += 4096;
  int* inv2   = q;  q += 2048;
  int* inv3   = q;  q += 1024;
  int* perm1  = q;  q += 2048;
  int* perm2  = q;  q += 1024;
  int* perm3  = q;  q += 512;

  float* zpart = (float*)A1b;
  u16*   yTh   = (u16*)A1bT;
  u16*   yTl   = (u16*)A1bT + 128 * 4096;

  const int E = 65536, N0 = 4096;

  // setup
  k_zeroi<<<(12292 + 255) / 256, 256, 0, stream>>>(iblk, 12292);
  k_detect<<<16, 256, 0, stream>>>((const u16*)x_in, ei, flags);
  k_loadall<<<(640256 + 255) / 256, 256, 0, stream>>>(x_in, Wd_in, bd_in, Wu_in, bu_in, pw_in,
                                                      xin, Wdf, bdf, Wuf, buf_, pwf, flags);
  k_degcnt<<<(E + 255) / 256, 256, 0, stream>>>(ei, E, N0, flags, indeg, outdeg, indeg2);
  k_scan3<<<1, 1024, 0, stream>>>(indeg, outdeg, indeg2, inoff, outoff, inoff2,
                                  incur, outcur, incur2, N0);
  k_csrfill<<<(E + 255) / 256, 256, 0, stream>>>(ei, E, N0, flags, incur, outcur, incur2,
                                                 inlist, outlist, inlist2);
  k_rowsort<<<N0 / 4, 256, 0, stream>>>(inoff2, inlist2, inlist2s, indeg2, dinv0, N0);

  // level-0 GCN (sparse, fused) + score for L1 pool
  k_xw<0, 0><<<N0 / 16, 256, 0, stream>>>(xin, nullptr, nullptr, nullptr, nullptr, nullptr,
                                          Wdf, dinv0, tmpY, nullptr, nullptr, N0);
  k_spmv<0, 1><<<N0 / 4, 256, 0, stream>>>(inoff2, inlist2s, tmpY, dinv0, bdf, pwf,
                                           xb0, nullptr, tsc, N0, 1, flags);

  // ---- level 1: sparse pool + dense GCN(2048) ----
  {
    int n = 4096, k = 2048;
    k_rank<<<n / 4, 256, 0, stream>>>(tsc, n, k, perm1, inv1);
    k_fill0<<<2048, 256, 0, stream>>>((float4*)A1p, (long)k * k / 4);
    int njoin = n / 4;
    k_spool<<<njoin + (E + 255) / 256, 256, 0, stream>>>(inoff, inlist, outoff, outlist, inv1, A1p,
                                                         k, n, njoin, ei, E, flags);
    k_dinv<<<k, 256, 0, stream>>>(A1p, dinv1, k);
    k_xw<1, 1><<<k / 16, 256, 0, stream>>>(xb0, nullptr, nullptr, perm1, nullptr, tsc,
                                           Wdf + 16384, dinv1, tmpY, yTh, yTl, k);
    k_zgemm_mfma<0><<<dim3(k / 128, 16), 256, 0, stream>>>(A1p, yTh, yTl, zpart, k, k / 16);
    k_epi<1><<<k / 4, 256, 0, stream>>>(zpart, tmpY, dinv1, bdf + 128, pwf + 128, xb1, tsc, k, 16, 1);
  }

  // ---- levels 2,3: dense MFMA pool + dense GCN ----
  {
    float* Acurs[2]  = {A1p, A2p};
    float* Anexts[2] = {A2p, A3p};
    int*   perms[2]  = {perm2, perm3};
    int*   invs[2]   = {inv2, inv3};
    float* xcurs[2]  = {xb1, xb2};
    float* xouts[2]  = {xb2, xb3};
    float* dinvs[2]  = {dinv2, dinv3};
    int    spoolS[2] = {4, 8};
    int    ns[2]     = {2048, 1024};
    for (int li = 0; li < 2; ++li) {
      int n = ns[li], k = n / 2, lvl = li + 2;
      k_rank<<<n / 4, 256, 0, stream>>>(tsc, n, k, perms[li], invs[li]);
      k_prep<<<dim3(n / 32, n / 32), 256, 0, stream>>>(Acurs[li], A1b, A1bT, n);
      float* Cn = Anexts[li];
      int Sp = spoolS[li];
      k_fill0<<<2048, 256, 0, stream>>>((float4*)Cn, (long)k * k / 4);
      k_mfma_pool<<<dim3(k / 128, k / 128, Sp), 256, 0, stream>>>(A1b, A1bT, perms[li], Cn, k, n, n / Sp);
      k_dinv<<<k, 256, 0, stream>>>(Cn, dinvs[li], k);
      int S = (k >= 2048) ? 16 : (k == 1024 ? 8 : 4);
      k_xw<1, 1><<<k / 16, 256, 0, stream>>>(xcurs[li], nullptr, nullptr, perms[li], nullptr, tsc,
                                             Wdf + lvl * 16384, dinvs[li], tmpY, yTh, yTl, k);
      k_zgemm_mfma<1><<<dim3(k / 128, S), 256, 0, stream>>>(Cn, yTh, yTl, zpart, k, k / S);
      if (li == 0)
        k_epi<1><<<k / 4, 256, 0, stream>>>(zpart, tmpY, dinvs[li], bdf + lvl * 128, pwf + lvl * 128,
                                            xouts[li], tsc, k, S, 1);
      else
        k_epi<0><<<k / 4, 256, 0, stream>>>(zpart, tmpY, dinvs[li], bdf + lvl * 128, nullptr,
                                            xouts[li], nullptr, k, S, 1);
    }
  }

  // ---- up path (dinv cached; unpool fused into xw) ----
  // up1: n=1024, A2p (alo=1)
  k_xw<2, 1><<<1024 / 16, 256, 0, stream>>>(nullptr, xb2, xb3, nullptr, inv3, nullptr,
                                            Wuf, dinv2, tmpY, yTh, yTl, 1024);
  k_zgemm_mfma<1><<<dim3(1024 / 128, 8), 256, 0, stream>>>(A2p, yTh, yTl, zpart, 1024, 1024 / 8);
  k_epi<0><<<1024 / 4, 256, 0, stream>>>(zpart, tmpY, dinv2, buf_, nullptr, xb2, nullptr, 1024, 8, 1);

  // up2: n=2048, A1p (alo=0)
  k_xw<2, 1><<<2048 / 16, 256, 0, stream>>>(nullptr, xb1, xb2, nullptr, inv2, nullptr,
                                            Wuf + 16384, dinv1, tmpY, yTh, yTl, 2048);
  k_zgemm_mfma<0><<<dim3(2048 / 128, 16), 256, 0, stream>>>(A1p, yTh, yTl, zpart, 2048, 2048 / 16);
  k_epi<0><<<2048 / 4, 256, 0, stream>>>(zpart, tmpY, dinv1, buf_ + 128, nullptr, xb1, nullptr, 2048, 16, 1);

  // up3: n=4096, sparse A0, final output (no act)
  k_xw<2, 0><<<N0 / 16, 256, 0, stream>>>(nullptr, xb0, xb1, nullptr, inv1, nullptr,
                                          Wuf + 2 * 16384, dinv0, tmpY, nullptr, nullptr, N0);
  k_spmv<1, 0><<<N0 / 4, 256, 0, stream>>>(inoff2, inlist2s, tmpY, dinv0, buf_ + 2 * 128, nullptr,
                                           nullptr, d_out, nullptr, N0, 0, flags);
}

// Round 13
// 358.112 us; speedup vs baseline: 1.1452x; 1.0153x over previous
//
#include <hip/hip_runtime.h>

typedef unsigned short u16;
typedef __attribute__((ext_vector_type(4))) short s16x4;
typedef __attribute__((ext_vector_type(8))) short s16x8;
typedef __attribute__((ext_vector_type(4))) float f32x4;

__device__ __forceinline__ float bf2f_(u16 b) { return __uint_as_float(((unsigned)b) << 16); }
__device__ __forceinline__ u16 f2bf_(float f) {
  unsigned u = __float_as_uint(f);
  return (u16)((u + 0x7FFFu + ((u >> 16) & 1u)) >> 16);
}

__device__ __forceinline__ void edge_decode(const int* ei, int e, int E, const int* flags,
                                            int& src, int& dst) {
  bool is64 = flags[1] < 100;
  src = is64 ? ei[2 * e] : ei[e];
  dst = is64 ? ei[2 * E + 2 * e] : ei[E + e];
}

// ---------------- setup ----------------
__global__ void k_zeroi(int* a, int n) {
  int i = blockIdx.x * 256 + threadIdx.x;
  if (i < n) a[i] = 0;
}

__global__ __launch_bounds__(256) void k_detect(const u16* __restrict__ xb,
                                                const int* __restrict__ ei,
                                                int* __restrict__ flags) {
  int i = blockIdx.x * 256 + threadIdx.x;  // 4096 threads
  int e8 = (xb[2 * i] >> 7) & 0xFF;
  int sane = (e8 >= 100 && e8 <= 140) ? 1 : 0;
  int nz = (ei[2 * i + 1] != 0) ? 1 : 0;
  #pragma unroll
  for (int off = 32; off; off >>= 1) { sane += __shfl_down(sane, off); nz += __shfl_down(nz, off); }
  if ((threadIdx.x & 63) == 0) { atomicAdd(&flags[0], sane); atomicAdd(&flags[1], nz); }
}

__global__ void k_loadall(const void* x, const void* wd, const void* bd, const void* wu,
                          const void* bu, const void* pw,
                          float* xin, float* Wdf, float* bdf, float* Wuf, float* buf_, float* pwf,
                          const int* __restrict__ flags) {
  int i = blockIdx.x * 256 + threadIdx.x;
  const void* src; float* dst; int off;
  if (i < 524288) { src = x; dst = xin; off = i; }
  else if (i < 589824) { src = wd; dst = Wdf; off = i - 524288; }
  else if (i < 590336) { src = bd; dst = bdf; off = i - 589824; }
  else if (i < 639488) { src = wu; dst = Wuf; off = i - 590336; }
  else if (i < 639872) { src = bu; dst = buf_; off = i - 639488; }
  else if (i < 640256) { src = pw; dst = pwf; off = i - 639872; }
  else return;
  bool isbf = flags[0] >= 2048;
  dst[off] = isbf ? bf2f_(((const u16*)src)[off]) : ((const float*)src)[off];
}

__global__ void k_fill0(float4* __restrict__ p, long n4) {
  long i = blockIdx.x * 256L + threadIdx.x;
  long stride = (long)gridDim.x * 256L;
  for (; i < n4; i += stride) p[i] = make_float4(0.f, 0.f, 0.f, 0.f);
}

// ---------------- CSR build ----------------
__global__ void k_degcnt(const int* __restrict__ ei, int E, int n, const int* __restrict__ flags,
                         int* __restrict__ indeg, int* __restrict__ outdeg, int* __restrict__ indeg2) {
  int e = blockIdx.x * 256 + threadIdx.x;
  if (e >= E) return;
  int src, dst; edge_decode(ei, e, E, flags, src, dst);
  if (src < 0 || src >= n || dst < 0 || dst >= n) return;
  atomicAdd(&indeg2[dst], 1);
  if (src == dst) return;
  atomicAdd(&indeg[dst], 1);
  atomicAdd(&outdeg[src], 1);
}

__global__ __launch_bounds__(1024) void k_scan3(const int* __restrict__ d0, const int* __restrict__ d1,
                                                const int* __restrict__ d2,
                                                int* o0, int* o1, int* o2,
                                                int* c0, int* c1, int* c2, int n) {
  __shared__ int part[1024];
  int t = threadIdx.x;
  int per = n / 1024;
  for (int pass = 0; pass < 3; ++pass) {
    const int* deg = pass == 0 ? d0 : (pass == 1 ? d1 : d2);
    int* off = pass == 0 ? o0 : (pass == 1 ? o1 : o2);
    int* cur = pass == 0 ? c0 : (pass == 1 ? c1 : c2);
    int local[8];
    int s = 0;
    for (int j = 0; j < per; ++j) { local[j] = s; s += deg[t * per + j]; }
    part[t] = s;
    __syncthreads();
    for (int d = 1; d < 1024; d <<= 1) {
      int v = (t >= d) ? part[t - d] : 0;
      __syncthreads();
      part[t] += v;
      __syncthreads();
    }
    int base = (t == 0) ? 0 : part[t - 1];
    for (int j = 0; j < per; ++j) {
      off[t * per + j] = base + local[j];
      cur[t * per + j] = base + local[j];
    }
    if (t == 1023) off[n] = part[1023];
    __syncthreads();
  }
}

__global__ void k_csrfill(const int* __restrict__ ei, int E, int n, const int* __restrict__ flags,
                          int* __restrict__ incur, int* __restrict__ outcur, int* __restrict__ incur2,
                          int* __restrict__ inlist, int* __restrict__ outlist, int* __restrict__ inlist2) {
  int e = blockIdx.x * 256 + threadIdx.x;
  if (e >= E) return;
  int src, dst; edge_decode(ei, e, E, flags, src, dst);
  if (src < 0 || src >= n || dst < 0 || dst >= n) return;
  inlist2[atomicAdd(&incur2[dst], 1)] = src;
  if (src == dst) return;
  inlist[atomicAdd(&incur[dst], 1)] = src;
  outlist[atomicAdd(&outcur[src], 1)] = dst;
}

// wave-parallel row sort (deterministic contents) + dinv0 from counts
__global__ __launch_bounds__(256) void k_rowsort(const int* __restrict__ inoff2,
                                                 const int* __restrict__ inlist2,
                                                 int* __restrict__ outlist2,
                                                 const int* __restrict__ indeg2,
                                                 float* __restrict__ dinv, int n) {
  int wave = threadIdx.x >> 6, lane = threadIdx.x & 63;
  int row = blockIdx.x * 4 + wave;
  if (row >= n) return;
  int ib = inoff2[row], ie = inoff2[row + 1];
  int L = ie - ib;
  for (int i = lane; i < L; i += 64) {
    int ki = inlist2[ib + i];
    int rank = 0;
    for (int j = 0; j < L; ++j) {
      int kj = inlist2[ib + j];
      rank += (kj < ki || (kj == ki && j < i)) ? 1 : 0;
    }
    outlist2[ib + rank] = ki;
  }
  if (lane == 0) dinv[row] = rsqrtf((float)indeg2[row] + 2.0f);
}

// ---------------- sparse L1 pool (join + 2*Ao edge term in one kernel) ----------------
__global__ __launch_bounds__(256) void k_spool(const int* __restrict__ inoff, const int* __restrict__ inlist,
                                               const int* __restrict__ outoff, const int* __restrict__ outlist,
                                               const int* __restrict__ inv, float* __restrict__ C,
                                               int M, int n, int njoin,
                                               const int* __restrict__ ei, int E, const int* __restrict__ flags) {
  int wave = threadIdx.x >> 6, lane = threadIdx.x & 63;
  if ((int)blockIdx.x < njoin) {
    int v = blockIdx.x * 4 + wave;
    if (v >= n) return;
    int ib = inoff[v], ni = inoff[v + 1] - ib;
    int ob = outoff[v], no = outoff[v + 1] - ob;
    int tot = ni * no;
    for (int p = lane; p < tot; p += 64) {
      int oi = p / ni, ii = p - oi * ni;
      int i = outlist[ob + oi];
      int j = inlist[ib + ii];
      if (i == j) continue;
      int ri = inv[i], rj = inv[j];
      if (ri >= 0 && rj >= 0) atomicAdd(&C[(size_t)ri * M + rj], 1.0f);
    }
  } else {
    int e = (blockIdx.x - njoin) * 256 + threadIdx.x;
    if (e >= E) return;
    int src, dst; edge_decode(ei, e, E, flags, src, dst);
    if (src < 0 || src >= n || dst < 0 || dst >= n || src == dst) return;
    int ri = inv[dst], rj = inv[src];
    if (ri >= 0 && rj >= 0) atomicAdd(&C[(size_t)ri * M + rj], 2.0f);
  }
}

// ---------------- dedicated dinv (full-grid rowsum; one block per row) ----------------
__global__ __launch_bounds__(256) void k_dinv(const float* __restrict__ A, float* __restrict__ dinv, int n) {
  int row = blockIdx.x;
  const float* r = A + (size_t)row * n;
  float s = 0.f;
  for (int j = threadIdx.x; j < n; j += 256) s += r[j];
  #pragma unroll
  for (int off = 32; off; off >>= 1) s += __shfl_down(s, off);
  __shared__ float red[4];
  int wave = threadIdx.x >> 6, lane = threadIdx.x & 63;
  if (lane == 0) red[wave] = s;
  __syncthreads();
  if (threadIdx.x == 0) {
    float deg = red[0] + red[1] + red[2] + red[3] + 2.0f;
    dinv[row] = rsqrtf(deg);
  }
}

// ---------------- fused xW kernel ----------------
// MODE: 0 plain x, 1 gather (x[perm[r]]*ts), 2 unpool (res[r]+prev[inv[r]])
// WT: 1 -> also write yTh/yTl bf16 hi/lo transpose chunks. dinv always read cached.
template<int MODE, int WT>
__global__ __launch_bounds__(256) void k_xw(const float* __restrict__ x, const float* __restrict__ res,
                                            const float* __restrict__ prev,
                                            const int* __restrict__ perm, const int* __restrict__ invm,
                                            const float* __restrict__ ts,
                                            const float* __restrict__ W,
                                            const float* __restrict__ dinv, float* __restrict__ yp,
                                            u16* __restrict__ yTh, u16* __restrict__ yTl, int n) {
  __shared__ float xs_[16 * 128];
  __shared__ float ds[16];
  int t = threadIdx.x;
  int row0 = blockIdx.x * 16;
  for (int e = t; e < 16 * 128; e += 256) {
    int r = e >> 7, c = e & 127;
    int gr = row0 + r;
    float v;
    if (MODE == 0) v = x[(size_t)gr * 128 + c];
    else if (MODE == 1) { int p0 = perm[gr]; v = x[(size_t)p0 * 128 + c] * ts[p0]; }
    else {
      int ir = invm[gr];
      v = res[(size_t)gr * 128 + c];
      if (ir >= 0) v += prev[(size_t)ir * 128 + c];
    }
    xs_[e] = v;
  }
  if (t < 16) ds[t] = dinv[row0 + t];
  __syncthreads();
  int c = t & 127, rh = t >> 7;
  float acc[8];
  #pragma unroll
  for (int ri = 0; ri < 8; ++ri) acc[ri] = 0.f;
  for (int k = 0; k < 128; ++k) {
    float wv = W[k * 128 + c];
    #pragma unroll
    for (int ri = 0; ri < 8; ++ri) acc[ri] += xs_[(rh * 8 + ri) * 128 + k] * wv;
  }
  s16x8 h, l;
  #pragma unroll
  for (int ri = 0; ri < 8; ++ri) {
    int r = row0 + rh * 8 + ri;
    float v = ds[rh * 8 + ri] * acc[ri];
    yp[(size_t)r * 128 + c] = v;
    if (WT) {
      u16 hb = f2bf_(v);
      h[ri] = (short)hb;
      l[ri] = (short)f2bf_(v - bf2f_(hb));
    }
  }
  if (WT) {
    int rbase = row0 + rh * 8;
    *(s16x8*)&yTh[(size_t)c * n + rbase] = h;
    *(s16x8*)&yTl[(size_t)c * n + rbase] = l;
  }
}

// ---------------- fused CSR SpMV + GCN epilogue (+optional score) ----------------
template<int FINAL, int SCORE>
__global__ __launch_bounds__(256) void k_spmv(const int* __restrict__ inoff2, const int* __restrict__ inlist2,
                                              const float* __restrict__ y, const float* __restrict__ dinv,
                                              const float* __restrict__ b, const float* __restrict__ w,
                                              float* __restrict__ outf, void* __restrict__ outv,
                                              float* __restrict__ ts,
                                              int n, int act, const int* __restrict__ flags) {
  int wave = threadIdx.x >> 6, lane = threadIdx.x & 63;
  int i = blockIdx.x * 4 + wave;
  if (i >= n) return;
  int ib = inoff2[i], ie = inoff2[i + 1];
  float z0 = 0.f, z1 = 0.f;
  for (int e = ib; e < ie; ++e) {
    int s = inlist2[e];
    z0 += y[(size_t)s * 128 + lane];
    z1 += y[(size_t)s * 128 + 64 + lane];
  }
  float di = dinv[i];
  float y0 = y[(size_t)i * 128 + lane], y1 = y[(size_t)i * 128 + 64 + lane];
  float v0 = di * (z0 + 2.0f * y0) + b[lane];
  float v1 = di * (z1 + 2.0f * y1) + b[64 + lane];
  if (act) { v0 = (v0 >= 0.f) ? v0 : 0.01f * v0; v1 = (v1 >= 0.f) ? v1 : 0.01f * v1; }
  if (FINAL) {
    if (flags[0] >= 2048) {
      ((u16*)outv)[(size_t)i * 128 + lane] = f2bf_(v0);
      ((u16*)outv)[(size_t)i * 128 + 64 + lane] = f2bf_(v1);
    } else {
      ((float*)outv)[(size_t)i * 128 + lane] = v0;
      ((float*)outv)[(size_t)i * 128 + 64 + lane] = v1;
    }
  } else {
    outf[(size_t)i * 128 + lane] = v0;
    outf[(size_t)i * 128 + 64 + lane] = v1;
  }
  if (SCORE) {
    float w0 = w[lane], w1 = w[64 + lane];
    float nr = w0 * w0 + w1 * w1;
    float dt = v0 * w0 + v1 * w1;
    #pragma unroll
    for (int off = 32; off; off >>= 1) { nr += __shfl_down(nr, off); dt += __shfl_down(dt, off); }
    if (lane == 0) ts[i] = tanhf(dt / sqrtf(nr));
  }
}

// ---------------- dense zgemm (n<=2048) ----------------
template<int ALO>
__global__ __launch_bounds__(256) void k_zgemm_mfma(const float* __restrict__ A,
                                                    const u16* __restrict__ yTh,
                                                    const u16* __restrict__ yTl,
                                                    float* __restrict__ zpart,
                                                    int n, int kchunk) {
  __shared__ __align__(16) u16 ah_[128 * 64];
  __shared__ __align__(16) u16 al_[ALO ? 128 * 64 : 8];
  __shared__ __align__(16) u16 bh_[128 * 64];
  __shared__ __align__(16) u16 bl_[128 * 64];
  int t = threadIdx.x;
  int row0 = blockIdx.x * 128;
  int s = blockIdx.y;
  int kbase = s * kchunk;
  int wave = t >> 6, lane = t & 63;
  int wr = wave >> 1, wc = wave & 1;
  int lrow = lane & 15, kb = lane >> 4;
  const f32x4 z4 = {0.f, 0.f, 0.f, 0.f};
  f32x4 acc[4][4];
  #pragma unroll
  for (int a = 0; a < 4; ++a)
    #pragma unroll
    for (int b = 0; b < 4; ++b) acc[a][b] = z4;

  for (int k0 = 0; k0 < kchunk; k0 += 64) {
    int koff = kbase + k0;
    __syncthreads();
    #pragma unroll
    for (int it = 0; it < 8; ++it) {
      int q = it * 256 + t;
      int r = q >> 4, i4 = q & 15;
      int g = i4 >> 1, h4 = (i4 & 1) * 4;
      float4 v = *(const float4*)&A[(size_t)(row0 + r) * n + koff + i4 * 4];
      float vv[4] = {v.x, v.y, v.z, v.w};
      s16x4 hh, ll;
      #pragma unroll
      for (int j = 0; j < 4; ++j) {
        u16 hb = f2bf_(vv[j]);
        hh[j] = (short)hb;
        if (ALO) ll[j] = (short)f2bf_(vv[j] - bf2f_(hb));
      }
      int ld = r * 64 + ((g ^ (r & 7)) << 3) + h4;
      *(s16x4*)&ah_[ld] = hh;
      if (ALO) *(s16x4*)&al_[ld] = ll;
    }
    #pragma unroll
    for (int it = 0; it < 4; ++it) {
      int q = it * 256 + t;
      int r = q >> 3, g = q & 7;
      int ld = r * 64 + ((g ^ (r & 7)) << 3);
      *(s16x8*)&bh_[ld] = *(const s16x8*)(yTh + (size_t)r * n + koff + g * 8);
      *(s16x8*)&bl_[ld] = *(const s16x8*)(yTl + (size_t)r * n + koff + g * 8);
    }
    __syncthreads();
    #pragma unroll
    for (int ks = 0; ks < 2; ++ks) {
      int gg = ks * 4 + kb;
      int gsw = (gg ^ (lrow & 7)) << 3;
      s16x8 af[4], alf[4], bhf[4], blf[4];
      #pragma unroll
      for (int mi = 0; mi < 4; ++mi) {
        int row = wr * 64 + mi * 16 + lrow;
        af[mi] = *(const s16x8*)&ah_[row * 64 + gsw];
        if (ALO) alf[mi] = *(const s16x8*)&al_[row * 64 + gsw];
      }
      #pragma unroll
      for (int ni = 0; ni < 4; ++ni) {
        int row = wc * 64 + ni * 16 + lrow;
        bhf[ni] = *(const s16x8*)&bh_[row * 64 + gsw];
        blf[ni] = *(const s16x8*)&bl_[row * 64 + gsw];
      }
      #pragma unroll
      for (int mi = 0; mi < 4; ++mi)
        #pragma unroll
        for (int ni = 0; ni < 4; ++ni) {
          acc[mi][ni] = __builtin_amdgcn_mfma_f32_16x16x32_bf16(af[mi], bhf[ni], acc[mi][ni], 0, 0, 0);
          acc[mi][ni] = __builtin_amdgcn_mfma_f32_16x16x32_bf16(af[mi], blf[ni], acc[mi][ni], 0, 0, 0);
          if (ALO) {
            acc[mi][ni] = __builtin_amdgcn_mfma_f32_16x16x32_bf16(alf[mi], bhf[ni], acc[mi][ni], 0, 0, 0);
            acc[mi][ni] = __builtin_amdgcn_mfma_f32_16x16x32_bf16(alf[mi], blf[ni], acc[mi][ni], 0, 0, 0);
          }
        }
    }
  }
  int rbase = (lane >> 4) * 4;
  #pragma unroll
  for (int mi = 0; mi < 4; ++mi)
    #pragma unroll
    for (int ni = 0; ni < 4; ++ni)
      #pragma unroll
      for (int j = 0; j < 4; ++j) {
        int gi = row0 + wr * 64 + mi * 16 + rbase + j;
        int gj = wc * 64 + ni * 16 + (lane & 15);
        zpart[((size_t)s * n + gi) * 128 + gj] = acc[mi][ni][j];
      }
}

// row-per-wave epilogue: v = dinv*(sum_s zpart + 2*yp) + b; leaky; optional score
template<int SCORE>
__global__ __launch_bounds__(256) void k_epi(const float* __restrict__ zpart, const float* __restrict__ yp,
                                             const float* __restrict__ dinv, const float* __restrict__ b,
                                             const float* __restrict__ w,
                                             float* __restrict__ outf, float* __restrict__ ts,
                                             int n, int S, int act) {
  int wave = threadIdx.x >> 6, lane = threadIdx.x & 63;
  int r = blockIdx.x * 4 + wave;
  if (r >= n) return;
  float z0 = 0.f, z1 = 0.f;
  for (int s = 0; s < S; ++s) {
    const float* zp = zpart + ((size_t)s * n + r) * 128;
    z0 += zp[lane];
    z1 += zp[64 + lane];
  }
  float di = dinv[r];
  float v0 = di * (z0 + 2.0f * yp[(size_t)r * 128 + lane]) + b[lane];
  float v1 = di * (z1 + 2.0f * yp[(size_t)r * 128 + 64 + lane]) + b[64 + lane];
  if (act) { v0 = (v0 >= 0.f) ? v0 : 0.01f * v0; v1 = (v1 >= 0.f) ? v1 : 0.01f * v1; }
  outf[(size_t)r * 128 + lane] = v0;
  outf[(size_t)r * 128 + 64 + lane] = v1;
  if (SCORE) {
    float w0 = w[lane], w1 = w[64 + lane];
    float nr = w0 * w0 + w1 * w1;
    float dt = v0 * w0 + v1 * w1;
    #pragma unroll
    for (int off = 32; off; off >>= 1) { nr += __shfl_down(nr, off); dt += __shfl_down(dt, off); }
    if (lane == 0) ts[r] = tanhf(dt / sqrtf(nr));
  }
}

// ---------------- top-k rank select ----------------
__global__ __launch_bounds__(256) void k_rank(const float* __restrict__ ts, int n, int k,
                                              int* __restrict__ perm, int* __restrict__ inv) {
  int wave = threadIdx.x >> 6, lane = threadIdx.x & 63;
  int i = blockIdx.x * 4 + wave;
  if (i >= n) return;
  unsigned bits = __float_as_uint(ts[i]);
  unsigned u = (bits & 0x80000000u) ? ~bits : (bits | 0x80000000u);
  unsigned long long my = ((unsigned long long)u << 32) | (unsigned)(0xFFFFFFFFu - (unsigned)i);
  int rank = 0;
  for (int j = lane; j < n; j += 64) {
    unsigned b2 = __float_as_uint(ts[j]);
    unsigned u2 = (b2 & 0x80000000u) ? ~b2 : (b2 | 0x80000000u);
    unsigned long long kj = ((unsigned long long)u2 << 32) | (unsigned)(0xFFFFFFFFu - (unsigned)j);
    rank += (kj > my) ? 1 : 0;
  }
  #pragma unroll
  for (int off = 32; off; off >>= 1) rank += __shfl_down(rank, off);
  if (lane == 0) {
    if (rank < k) perm[rank] = i;
    inv[i] = (rank < k) ? rank : -1;
  }
}

// ---------------- dense augment for L2/L3 ----------------
__global__ __launch_bounds__(256) void k_prep(const float* __restrict__ A, u16* __restrict__ A1,
                                              u16* __restrict__ A1T, int n) {
  __shared__ float tile[32][33];
  int bi = blockIdx.y, bj = blockIdx.x;
  int tx = threadIdx.x & 31, ty = threadIdx.x >> 5;
  int r0 = bi * 32, c0 = bj * 32;
  #pragma unroll
  for (int yy = 0; yy < 4; ++yy) {
    int r = ty * 4 + yy;
    int gr = r0 + r, gc = c0 + tx;
    float v = A[(size_t)gr * n + gc];
    if (gr == gc) v = 1.0f;
    tile[r][tx] = v;
    A1[(size_t)gr * n + gc] = f2bf_(v);
  }
  __syncthreads();
  #pragma unroll
  for (int yy = 0; yy < 4; ++yy) {
    int r = ty * 4 + yy;
    int gr = c0 + r, gc = r0 + tx;
    A1T[(size_t)gr * n + gc] = f2bf_(tile[tx][r]);
  }
}

// dense pool (L2/L3): split-K atomicAdd (exact integers); diag skipped (stays 0 from fill)
__global__ __launch_bounds__(256) void k_mfma_pool(const u16* __restrict__ A1, const u16* __restrict__ A1T,
                                                   const int* __restrict__ perm, float* __restrict__ C,
                                                   int M, int K, int kchunk) {
  __shared__ __align__(16) u16 a_lds[128 * 64];
  __shared__ __align__(16) u16 b_lds[128 * 64];
  __shared__ int pr[128], pc[128];
  int t = threadIdx.x;
  int br = blockIdx.x, bc = blockIdx.y;
  int kbase = blockIdx.z * kchunk;
  if (t < 128) pr[t] = perm[br * 128 + t];
  else pc[t - 128] = perm[bc * 128 + (t - 128)];
  __syncthreads();
  int wave = t >> 6, lane = t & 63;
  int wr = wave >> 1, wc = wave & 1;
  int lrow = lane & 15, kb = lane >> 4;
  const f32x4 z4 = {0.f, 0.f, 0.f, 0.f};
  f32x4 acc[4][4];
  #pragma unroll
  for (int a = 0; a < 4; ++a)
    #pragma unroll
    for (int b = 0; b < 4; ++b) acc[a][b] = z4;

  for (int k0 = 0; k0 < kchunk; k0 += 64) {
    int koff = kbase + k0;
    __syncthreads();
    #pragma unroll
    for (int it = 0; it < 4; ++it) {
      int q = it * 256 + t;
      int r = q >> 3, g = q & 7;
      int ld = r * 64 + ((g ^ (r & 7)) << 3);
      *(s16x8*)&a_lds[ld] = *(const s16x8*)(A1 + (size_t)pr[r] * K + koff + g * 8);
      *(s16x8*)&b_lds[ld] = *(const s16x8*)(A1T + (size_t)pc[r] * K + koff + g * 8);
    }
    __syncthreads();
    #pragma unroll
    for (int ks = 0; ks < 2; ++ks) {
      int gg = ks * 4 + kb;
      int gsw = (gg ^ (lrow & 7)) << 3;
      s16x8 af[4], bfv[4];
      #pragma unroll
      for (int mi = 0; mi < 4; ++mi)
        af[mi] = *(const s16x8*)&a_lds[(wr * 64 + mi * 16 + lrow) * 64 + gsw];
      #pragma unroll
      for (int ni = 0; ni < 4; ++ni)
        bfv[ni] = *(const s16x8*)&b_lds[(wc * 64 + ni * 16 + lrow) * 64 + gsw];
      #pragma unroll
      for (int mi = 0; mi < 4; ++mi)
        #pragma unroll
        for (int ni = 0; ni < 4; ++ni)
          acc[mi][ni] = __builtin_amdgcn_mfma_f32_16x16x32_bf16(af[mi], bfv[ni], acc[mi][ni], 0, 0, 0);
    }
  }
  int rbase = (lane >> 4) * 4;
  #pragma unroll
  for (int mi = 0; mi < 4; ++mi)
    #pragma unroll
    for (int ni = 0; ni < 4; ++ni)
      #pragma unroll
      for (int j = 0; j < 4; ++j) {
        int gi = br * 128 + wr * 64 + mi * 16 + rbase + j;
        int gj = bc * 128 + wc * 64 + ni * 16 + (lane & 15);
        if (gi != gj) atomicAdd(&C[(size_t)gi * M + gj], acc[mi][ni][j]);
      }
}

// ---------------- driver ----------------
extern "C" void kernel_launch(void* const* d_in, const int* in_sizes, int n_in,
                              void* d_out, int out_size, void* d_ws, size_t ws_size,
                              hipStream_t stream) {
  (void)in_sizes; (void)n_in; (void)out_size; (void)ws_size;
  const void* x_in  = d_in[0];
  const int*  ei    = (const int*)d_in[1];
  const void* Wd_in = d_in[2];
  const void* bd_in = d_in[3];
  const void* Wu_in = d_in[4];
  const void* bu_in = d_in[5];
  const void* pw_in = d_in[6];

  char* p = (char*)d_ws;
  auto alloc = [&](size_t bytes) { char* r = p; p += (bytes + 255) & ~(size_t)255; return r; };
  float* A1p  = (float*)alloc(2048ull * 2048 * 4);   // A1p,A2p,A3p contiguous -> one zero-fill
  float* A2p  = (float*)alloc(1024ull * 1024 * 4);
  float* A3p  = (float*)alloc(512ull * 512 * 4);
  u16*   A1b  = (u16*)alloc(4096ull * 4096 * 2);   // L2/L3 pool src; zpart aliases during GCNs
  u16*   A1bT = (u16*)alloc(4096ull * 4096 * 2);   // L2/L3 pool src^T; yTh/yTl alias during GCNs
  float* xb0  = (float*)alloc(4096 * 128 * 4);
  float* xb1  = (float*)alloc(2048 * 128 * 4);
  float* xb2  = (float*)alloc(1024 * 128 * 4);
  float* xb3  = (float*)alloc(512 * 128 * 4);
  float* xin  = (float*)alloc(4096 * 128 * 4);
  float* tmpY = (float*)alloc(4096 * 128 * 4);
  float* dinv0 = (float*)alloc(4096 * 4);
  float* dinv1 = (float*)alloc(2048 * 4);
  float* dinv2 = (float*)alloc(1024 * 4);
  float* dinv3 = (float*)alloc(512 * 4);
  float* tsc  = (float*)alloc(4096 * 4);
  float* Wdf  = (float*)alloc(4 * 128 * 128 * 4);
  float* bdf  = (float*)alloc(4 * 128 * 4);
  float* Wuf  = (float*)alloc(3 * 128 * 128 * 4);
  float* buf_ = (float*)alloc(3 * 128 * 4);
  float* pwf  = (float*)alloc(3 * 128 * 4);
  int* iblk = (int*)alloc((12292 + 3 * 4097 + 3 * 4096 + 4 * 65536 + 4096 + 2048 + 1024 + 2048 + 1024 + 512) * 4);
  int* flags  = iblk;
  int* indeg  = iblk + 4;
  int* outdeg = iblk + 4100;
  int* indeg2 = iblk + 8196;
  int* q      = iblk + 12292;
  int* inoff  = q;  q += 4097;
  int* outoff = q;  q += 4097;
  int* inoff2 = q;  q += 4097;
  int* incur  = q;  q += 4096;
  int* outcur = q;  q += 4096;
  int* incur2 = q;  q += 4096;
  int* inlist = q;  q += 65536;
  int* outlist= q;  q += 65536;
  int* inlist2= q;  q += 65536;
  int* inlist2s = q; q += 65536;
  int* inv1   = q;  q += 4096;
  int* inv2   = q;  q += 2048;
  int* inv3   = q;  q += 1024;
  int* perm1  = q;  q += 2048;
  int* perm2  = q;  q += 1024;
  int* perm3  = q;  q += 512;

  float* zpart = (float*)A1b;
  u16*   yTh   = (u16*)A1bT;
  u16*   yTl   = (u16*)A1bT + 128 * 4096;

  const int E = 65536, N0 = 4096;

  // setup
  k_zeroi<<<(12292 + 255) / 256, 256, 0, stream>>>(iblk, 12292);
  k_detect<<<16, 256, 0, stream>>>((const u16*)x_in, ei, flags);
  k_loadall<<<(640256 + 255) / 256, 256, 0, stream>>>(x_in, Wd_in, bd_in, Wu_in, bu_in, pw_in,
                                                      xin, Wdf, bdf, Wuf, buf_, pwf, flags);
  k_degcnt<<<(E + 255) / 256, 256, 0, stream>>>(ei, E, N0, flags, indeg, outdeg, indeg2);
  k_scan3<<<1, 1024, 0, stream>>>(indeg, outdeg, indeg2, inoff, outoff, inoff2,
                                  incur, outcur, incur2, N0);
  k_csrfill<<<(E + 255) / 256, 256, 0, stream>>>(ei, E, N0, flags, incur, outcur, incur2,
                                                 inlist, outlist, inlist2);
  k_rowsort<<<N0 / 4, 256, 0, stream>>>(inoff2, inlist2, inlist2s, indeg2, dinv0, N0);
  // zero all pooled-A buffers at once (contiguous; all fills precede their pool writes)
  k_fill0<<<2048, 256, 0, stream>>>((float4*)A1p, (long)(2048 * 2048 + 1024 * 1024 + 512 * 512) / 4);

  // level-0 GCN (sparse, fused) + score for L1 pool
  k_xw<0, 0><<<N0 / 16, 256, 0, stream>>>(xin, nullptr, nullptr, nullptr, nullptr, nullptr,
                                          Wdf, dinv0, tmpY, nullptr, nullptr, N0);
  k_spmv<0, 1><<<N0 / 4, 256, 0, stream>>>(inoff2, inlist2s, tmpY, dinv0, bdf, pwf,
                                           xb0, nullptr, tsc, N0, 1, flags);

  // ---- level 1: sparse pool + dense GCN(2048) ----
  {
    int n = 4096, k = 2048;
    k_rank<<<n / 4, 256, 0, stream>>>(tsc, n, k, perm1, inv1);
    int njoin = n / 4;
    k_spool<<<njoin + (E + 255) / 256, 256, 0, stream>>>(inoff, inlist, outoff, outlist, inv1, A1p,
                                                         k, n, njoin, ei, E, flags);
    k_dinv<<<k, 256, 0, stream>>>(A1p, dinv1, k);
    k_xw<1, 1><<<k / 16, 256, 0, stream>>>(xb0, nullptr, nullptr, perm1, nullptr, tsc,
                                           Wdf + 16384, dinv1, tmpY, yTh, yTl, k);
    k_zgemm_mfma<0><<<dim3(k / 128, 16), 256, 0, stream>>>(A1p, yTh, yTl, zpart, k, k / 16);
    k_epi<1><<<k / 4, 256, 0, stream>>>(zpart, tmpY, dinv1, bdf + 128, pwf + 128, xb1, tsc, k, 16, 1);
  }

  // ---- levels 2,3: dense MFMA pool + dense GCN ----
  {
    float* Acurs[2]  = {A1p, A2p};
    float* Anexts[2] = {A2p, A3p};
    int*   perms[2]  = {perm2, perm3};
    int*   invs[2]   = {inv2, inv3};
    float* xcurs[2]  = {xb1, xb2};
    float* xouts[2]  = {xb2, xb3};
    float* dinvs[2]  = {dinv2, dinv3};
    int    spoolS[2] = {4, 8};
    int    ns[2]     = {2048, 1024};
    for (int li = 0; li < 2; ++li) {
      int n = ns[li], k = n / 2, lvl = li + 2;
      k_rank<<<n / 4, 256, 0, stream>>>(tsc, n, k, perms[li], invs[li]);
      k_prep<<<dim3(n / 32, n / 32), 256, 0, stream>>>(Acurs[li], A1b, A1bT, n);
      float* Cn = Anexts[li];
      int Sp = spoolS[li];
      k_mfma_pool<<<dim3(k / 128, k / 128, Sp), 256, 0, stream>>>(A1b, A1bT, perms[li], Cn, k, n, n / Sp);
      k_dinv<<<k, 256, 0, stream>>>(Cn, dinvs[li], k);
      int S = (k >= 2048) ? 16 : (k == 1024 ? 8 : 4);
      k_xw<1, 1><<<k / 16, 256, 0, stream>>>(xcurs[li], nullptr, nullptr, perms[li], nullptr, tsc,
                                             Wdf + lvl * 16384, dinvs[li], tmpY, yTh, yTl, k);
      k_zgemm_mfma<1><<<dim3(k / 128, S), 256, 0, stream>>>(Cn, yTh, yTl, zpart, k, k / S);
      if (li == 0)
        k_epi<1><<<k / 4, 256, 0, stream>>>(zpart, tmpY, dinvs[li], bdf + lvl * 128, pwf + lvl * 128,
                                            xouts[li], tsc, k, S, 1);
      else
        k_epi<0><<<k / 4, 256, 0, stream>>>(zpart, tmpY, dinvs[li], bdf + lvl * 128, nullptr,
                                            xouts[li], nullptr, k, S, 1);
    }
  }

  // ---- up path (dinv cached; unpool fused into xw) ----
  // up1: n=1024, A2p (alo=1)
  k_xw<2, 1><<<1024 / 16, 256, 0, stream>>>(nullptr, xb2, xb3, nullptr, inv3, nullptr,
                                            Wuf, dinv2, tmpY, yTh, yTl, 1024);
  k_zgemm_mfma<1><<<dim3(1024 / 128, 8), 256, 0, stream>>>(A2p, yTh, yTl, zpart, 1024, 1024 / 8);
  k_epi<0><<<1024 / 4, 256, 0, stream>>>(zpart, tmpY, dinv2, buf_, nullptr, xb2, nullptr, 1024, 8, 1);

  // up2: n=2048, A1p (alo=0)
  k_xw<2, 1><<<2048 / 16, 256, 0, stream>>>(nullptr, xb1, xb2, nullptr, inv2, nullptr,
                                            Wuf + 16384, dinv1, tmpY, yTh, yTl, 2048);
  k_zgemm_mfma<0><<<dim3(2048 / 128, 16), 256, 0, stream>>>(A1p, yTh, yTl, zpart, 2048, 2048 / 16);
  k_epi<0><<<2048 / 4, 256, 0, stream>>>(zpart, tmpY, dinv1, buf_ + 128, nullptr, xb1, nullptr, 2048, 16, 1);

  // up3: n=4096, sparse A0, final output (no act)
  k_xw<2, 0><<<N0 / 16, 256, 0, stream>>>(nullptr, xb0, xb1, nullptr, inv1, nullptr,
                                          Wuf + 2 * 16384, dinv0, tmpY, nullptr, nullptr, N0);
  k_spmv<1, 0><<<N0 / 4, 256, 0, stream>>>(inoff2, inlist2s, tmpY, dinv0, buf_ + 2 * 128, nullptr,
                                           nullptr, d_out, nullptr, N0, 0, flags);
}